// Round 4
// baseline (599.092 us; speedup 1.0000x reference)
//
#include <hip/hip_runtime.h>
#include <stdint.h>

typedef __bf16 bf16x8 __attribute__((ext_vector_type(8)));
typedef __bf16 bf16x4 __attribute__((ext_vector_type(4)));
typedef float f32x4v __attribute__((ext_vector_type(4)));

__device__ __forceinline__ void async_copy16(const void* gptr, void* ldsptr) {
  // wave-uniform LDS base; HW scatters lane i to base + i*16
  __builtin_amdgcn_global_load_lds(
      (const __attribute__((address_space(1))) void*)gptr,
      (__attribute__((address_space(3))) void*)ldsptr,
      16, 0, 0);
}

// ---------------------------------------------------------------------------
// f32 -> (hi, lo) bf16 split: hi = bf16(x), lo = bf16(x - hi). rep err ~2^-17.
// ---------------------------------------------------------------------------
__global__ __launch_bounds__(256) void cvt_split(
    const float* __restrict__ src, __bf16* __restrict__ hi,
    __bf16* __restrict__ lo, int n4) {
  const int i = blockIdx.x * 256 + threadIdx.x;
  if (i < n4) {
    const float4 v = ((const float4*)src)[i];
    float vv[4] = {v.x, v.y, v.z, v.w};
    bf16x4 h, l;
    for (int j = 0; j < 4; ++j) {
      h[j] = (__bf16)vv[j];
      l[j] = (__bf16)(vv[j] - (float)h[j]);
    }
    ((bf16x4*)hi)[i] = h;
    ((bf16x4*)lo)[i] = l;
  }
}

// ---------------------------------------------------------------------------
// QKV projection, round-4: dbuf + corrected swizzle. C=(Ah+Al)@(Bh+Bl)^T.
// 64-B LDS rows: addr mod 128 = (row&1)*64 + slot*16 -> row parity is a free
// address bit; correct involution is slot ^= (row>>1)&3 (round-3's row&3 gave
// 4-way conflicts). Double-buffered BK=32 (64 KB LDS, 2 blocks/CU): stage t+1
// issued at top of tile t, drained by tile-end __syncthreads (issue-early).
// n-stripe XCD map: XCD x owns n-panels [4x,4x+4) -> B stripe 4MB = one L2.
// grid 1024 (1D), block 256 (4 waves, 2x2, 4x4 16x16x32 MFMA, 64x64/wave).
// ---------------------------------------------------------------------------
__global__ __launch_bounds__(256, 2) void gemm_qkv(
    const __bf16* __restrict__ Ah, const __bf16* __restrict__ Al,
    const __bf16* __restrict__ Bh, const __bf16* __restrict__ Bl,
    float* __restrict__ C) {
  const int K = 2048, ldc = 4096;
  __shared__ __align__(16) __bf16 Ash[2][128 * 32];
  __shared__ __align__(16) __bf16 Asl[2][128 * 32];
  __shared__ __align__(16) __bf16 Bsh[2][128 * 32];
  __shared__ __align__(16) __bf16 Bsl[2][128 * 32];
  // n-stripe XCD map (round-robin dispatch: XCD = bid & 7):
  // XCD x -> n_blk = 4x + (c&3), m_blk = c>>2  (bijective over 1024 blocks)
  const int bid = blockIdx.x;
  const int xcd = bid & 7, c = bid >> 3;
  const int m0 = (c >> 2) * 128, n0 = (xcd * 4 + (c & 3)) * 128;
  const int tid = threadIdx.x;
  const int wid = tid >> 6, lane = tid & 63, l15 = lane & 15, quad = lane >> 4;
  const int wm = wid >> 1, wn = wid & 1;

  f32x4v acc[4][4] = {};

  // stage one BK=32 tile of all 4 planes into buf: 512 16B-chunks/plane.
  // phys chunk cc (linear LDS) holds global (row cc>>2, slot (cc&3)^((row>>1)&3))
  auto stage = [&](int buf, int kb) {
    for (int it = 0; it < 2; ++it) {
      const int cc = (wid * 2 + it) * 64 + lane;
      const int row = cc >> 2;
      const int sc = (cc & 3) ^ ((row >> 1) & 3);
      const size_t ao = (size_t)(m0 + row) * K + kb + sc * 8;
      const size_t bo = (size_t)(n0 + row) * K + kb + sc * 8;
      const int dst = (wid * 2 + it) * 512;
      async_copy16(Ah + ao, &Ash[buf][dst]);
      async_copy16(Al + ao, &Asl[buf][dst]);
      async_copy16(Bh + bo, &Bsh[buf][dst]);
      async_copy16(Bl + bo, &Bsl[buf][dst]);
    }
  };

  stage(0, 0);
  __syncthreads();  // drains prologue vmcnt -> buf0 complete

  for (int t = 0; t < 64; ++t) {
    const int buf = t & 1;
    if (t < 63) stage(buf ^ 1, (t + 1) * 32);  // issue-early prefetch
    bf16x8 afh[4], afl[4], bfh[4], bfl[4];
    for (int mt = 0; mt < 4; ++mt) {
      const int r = wm * 64 + mt * 16 + l15;
      const int o = r * 32 + ((quad ^ ((r >> 1) & 3)) * 8);  // swizzled read
      afh[mt] = *(const bf16x8*)&Ash[buf][o];
      afl[mt] = *(const bf16x8*)&Asl[buf][o];
    }
    for (int nt = 0; nt < 4; ++nt) {
      const int r = wn * 64 + nt * 16 + l15;
      const int o = r * 32 + ((quad ^ ((r >> 1) & 3)) * 8);
      bfh[nt] = *(const bf16x8*)&Bsh[buf][o];
      bfl[nt] = *(const bf16x8*)&Bsl[buf][o];
    }
    for (int mt = 0; mt < 4; ++mt)
      for (int nt = 0; nt < 4; ++nt) {
        acc[mt][nt] = __builtin_amdgcn_mfma_f32_16x16x32_bf16(afh[mt], bfh[nt], acc[mt][nt], 0, 0, 0);
        acc[mt][nt] = __builtin_amdgcn_mfma_f32_16x16x32_bf16(afh[mt], bfl[nt], acc[mt][nt], 0, 0, 0);
        acc[mt][nt] = __builtin_amdgcn_mfma_f32_16x16x32_bf16(afl[mt], bfh[nt], acc[mt][nt], 0, 0, 0);
      }
    __syncthreads();  // drains prefetch vmcnt (t+1 ready) + releases buf
  }
  // C/D layout: col = lane&15, row = quad*4 + reg
  for (int mt = 0; mt < 4; ++mt)
    for (int nt = 0; nt < 4; ++nt) {
      const int row = m0 + wm * 64 + mt * 16 + quad * 4;
      const int col = n0 + wn * 64 + nt * 16 + l15;
      for (int r = 0; r < 4; ++r)
        C[(size_t)(row + r) * ldc + col] = acc[mt][nt][r];
    }
}

// ---------------------------------------------------------------------------
// RMSNorm + RoPE, f32 internal. grid (4096, 16), block 64 (one wave).
// chunk 0..7 -> q head (hi/lo planes), 8..11 -> k head (hi/lo planes),
// 12..15 -> v head (norm only, bf16, TRANSPOSED [kvh][256][S] for PV).
// [validated round 6]
// ---------------------------------------------------------------------------
__global__ __launch_bounds__(64) void norm_rope(
    const float* __restrict__ qkv, const float* __restrict__ cosb,
    const float* __restrict__ sinb, const float* __restrict__ qnw,
    const float* __restrict__ knw,
    __bf16* __restrict__ qh, __bf16* __restrict__ ql,
    __bf16* __restrict__ kh, __bf16* __restrict__ kl,
    __bf16* __restrict__ vT) {
  const int s = blockIdx.x, c = blockIdx.y, lane = threadIdx.x;
  const int d0 = lane * 4;
  const float4 xv = *(const float4*)(qkv + (size_t)s * 4096 + c * 256 + d0);
  float v[4] = {xv.x, xv.y, xv.z, xv.w};
  float ss = v[0] * v[0] + v[1] * v[1] + v[2] * v[2] + v[3] * v[3];
  for (int off = 1; off < 64; off <<= 1) ss += __shfl_xor(ss, off);
  const float rn = rsqrtf(ss * (1.0f / 256.0f) + 1e-6f);
  if (c < 12) {
    const float* w = (c < 8) ? qnw : knw;
    float y[4], yp[4];
    for (int j = 0; j < 4; ++j) y[j] = v[j] * rn * w[d0 + j];
    for (int j = 0; j < 4; ++j) yp[j] = __shfl_xor(y[j], 32);  // d partner +/-128
    for (int j = 0; j < 4; ++j) {
      const int d = d0 + j;
      const float rot = (d < 128) ? -yp[j] : yp[j];
      y[j] = y[j] * cosb[s * 256 + d] + rot * sinb[s * 256 + d];
    }
    const size_t o = (c < 8) ? ((size_t)c * 4096 + s) * 256 + d0
                             : ((size_t)(c - 8) * 4096 + s) * 256 + d0;
    __bf16* dh = (c < 8) ? qh : kh;
    __bf16* dl = (c < 8) ? ql : kl;
    bf16x4 hv, lv;
    for (int j = 0; j < 4; ++j) {
      hv[j] = (__bf16)y[j];
      lv[j] = (__bf16)(y[j] - (float)hv[j]);
    }
    *(bf16x4*)(dh + o) = hv;
    *(bf16x4*)(dl + o) = lv;
  } else {
    const int kvh = c - 12;
    for (int j = 0; j < 4; ++j)
      vT[(size_t)(kvh * 256 + d0 + j) * 4096 + s] = (__bf16)(v[j] * rn);
  }
}

// ---------------------------------------------------------------------------
// MFMA flash attention, sliding window 1024, causal, NO softmax scale.
// QK^T split-precision (hi*hi + hi*lo + lo*hi); PV bf16.
// 8-wave block, QBLK=128, KVBLK=32, double-buffered global_load_lds staging.
// Round-4: V and P tiles get the stride-64B involution (chunk ^= (row>>1)&3)
// -- both were 8-way bank-conflicted (slot fixed=quad for even-row lanes).
// K planes keep ^(row&7) (512-B rows, verified free). grid (32,8), block 512.
// ---------------------------------------------------------------------------
__global__ __launch_bounds__(512, 2) void attn_mfma(
    const __bf16* __restrict__ Qh_, const __bf16* __restrict__ Ql_,
    const __bf16* __restrict__ Kh_, const __bf16* __restrict__ Kl_,
    const __bf16* __restrict__ VT, __bf16* __restrict__ Aout) {
  const int S = 4096, D = 256;
  // bijective remap: block (x + 32*y) -> XCD (bid&7) handles head (bid&7)
  const int bid = blockIdx.y * 32 + blockIdx.x;
  const int swz = (bid & 7) * 32 + (bid >> 3);
  const int h = swz >> 5;
  const int q0 = (swz & 31) * 128;
  const int tid = threadIdx.x;
  const int wid = tid >> 6, lane = tid & 63, l15 = lane & 15, quad = lane >> 4;
  const int kv = h >> 1;

  // double-buffered KV tiles: Kh/Kl [32 keys][256 d] (swizzled), V [256 d][32 keys]
  __shared__ __align__(16) __bf16 Ksh[2][32 * 256];
  __shared__ __align__(16) __bf16 Ksl[2][32 * 256];
  __shared__ __align__(16) __bf16 Vs[2][256 * 32];
  __shared__ __align__(16) __bf16 P[8][16][32];  // per-wave P C->A round-trip

  const __bf16* Khh = Kh_ + (size_t)kv * S * D;
  const __bf16* Khl = Kl_ + (size_t)kv * S * D;
  const __bf16* Vh = VT + (size_t)kv * D * S;

  // stage one 32-key tile: 1024 16B-chunks per plane, 2 chunks/thread/plane.
  // K chunk n: row=n>>5, c=n&31; LDS holds global chunk (row, c ^ (row&7)).
  // V chunk n: dim=n>>2, kc=n&3; LDS holds global chunk (dim, kc ^ ((dim>>1)&3)).
  auto stage = [&](int buf, int kt) {
    for (int set = 0; set < 2; ++set) {
      const int n = set * 512 + wid * 64 + lane;
      const int row = n >> 5, c = n & 31;
      const int sc = c ^ (row & 7);
      const size_t go = (size_t)(kt + row) * D + sc * 8;
      const int dst = (set * 512 + wid * 64) * 8;  // wave-uniform LDS base
      async_copy16(Khh + go, &Ksh[buf][dst]);
      async_copy16(Khl + go, &Ksl[buf][dst]);
      const int dim = n >> 2, kc = n & 3;
      const size_t vo = (size_t)dim * S + kt + (kc ^ ((dim >> 1) & 3)) * 8;
      async_copy16(Vh + vo, &Vs[buf][dst]);
    }
  };

  // Q fragments hi/lo (A-layout: m=lane&15, k=quad*8+j)
  bf16x8 qfh[8], qfl[8];
  {
    const size_t qoff =
        (size_t)h * S * D + (size_t)(q0 + wid * 16 + l15) * D + quad * 8;
    for (int ks = 0; ks < 8; ++ks) {
      qfh[ks] = *(const bf16x8*)(Qh_ + qoff + ks * 32);
      qfl[ks] = *(const bf16x8*)(Ql_ + qoff + ks * 32);
    }
  }

  f32x4v O[16] = {};
  float mrow[4] = {-1e30f, -1e30f, -1e30f, -1e30f};
  float lrow[4] = {0.f, 0.f, 0.f, 0.f};

  const int lo = (q0 >= 1024) ? (q0 - 1024) : 0;
  const int hi = q0 + 96;  // last 32-key tile base for QBLK=128
  const int iqmin = q0 + wid * 16;
  const int iqmax = iqmin + 15;

  stage(0, lo);
  __syncthreads();
  int cur = 0;

  for (int kt = lo; kt <= hi; kt += 32) {
    if (kt + 32 <= hi) stage(cur ^ 1, kt + 32);  // async prefetch next tile
    // wave-uniform skip of fully-masked tiles (must still hit the barrier)
    const bool active = (kt <= iqmax) && (kt + 31 >= iqmin - 1023);
    if (active) {
      // scores [16 q x 32 keys]: 2 n-tiles x 8 k-steps x 3 split terms
      f32x4v sa[2] = {};
      for (int nt = 0; nt < 2; ++nt) {
        const int row = nt * 16 + l15;
        const int rxk = row & 7;
        for (int ks = 0; ks < 8; ++ks) {
          const int c = (ks * 4 + quad) ^ rxk;
          const bf16x8 kh8 = *(const bf16x8*)&Ksh[cur][row * 256 + c * 8];
          const bf16x8 kl8 = *(const bf16x8*)&Ksl[cur][row * 256 + c * 8];
          sa[nt] = __builtin_amdgcn_mfma_f32_16x16x32_bf16(qfh[ks], kh8, sa[nt], 0, 0, 0);
          sa[nt] = __builtin_amdgcn_mfma_f32_16x16x32_bf16(qfh[ks], kl8, sa[nt], 0, 0, 0);
          sa[nt] = __builtin_amdgcn_mfma_f32_16x16x32_bf16(qfl[ks], kh8, sa[nt], 0, 0, 0);
        }
      }
      // online softmax (C-layout: row = quad*4+r, col = l15 within n-tile)
      float al[4];
      for (int r = 0; r < 4; ++r) {
        const int i = q0 + wid * 16 + quad * 4 + r;
        float mx = -1e30f;
        for (int nt = 0; nt < 2; ++nt) {
          const int j = kt + nt * 16 + l15;
          const float svv = ((j <= i) && (i - j < 1024)) ? sa[nt][r] : -1e30f;
          sa[nt][r] = svv;
          mx = fmaxf(mx, svv);
        }
        for (int off = 1; off < 16; off <<= 1) mx = fmaxf(mx, __shfl_xor(mx, off));
        const float mn = fmaxf(mrow[r], mx);
        al[r] = __expf(mrow[r] - mn);
        float ps = 0.f;
        const int prow = quad * 4 + r;
        const int px = (prow >> 1) & 3;
        for (int nt = 0; nt < 2; ++nt) {
          // explicit zero for fully-masked history (else exp(0)=1 garbage)
          const float p = (mn <= -1e29f) ? 0.f : __expf(sa[nt][r] - mn);
          const int pc = (nt * 2 + (l15 >> 3)) ^ px;  // swizzled P column chunk
          P[wid][prow][pc * 8 + (l15 & 7)] = (__bf16)p;
          ps += p;
        }
        for (int off = 1; off < 16; off <<= 1) ps += __shfl_xor(ps, off);
        lrow[r] = lrow[r] * al[r] + ps;
        mrow[r] = mn;
      }
      for (int nt2 = 0; nt2 < 16; ++nt2)
        for (int r = 0; r < 4; ++r) O[nt2][r] *= al[r];
      __asm__ volatile("s_waitcnt lgkmcnt(0)" ::: "memory");
      __builtin_amdgcn_sched_barrier(0);
      // PV: A = P[16x32] (A-layout from LDS, swizzled), B from staged V tile
      const int prx = (l15 >> 1) & 3;
      const bf16x8 pf = *(const bf16x8*)&P[wid][l15][(quad ^ prx) * 8];
      for (int nt2 = 0; nt2 < 16; ++nt2) {
        const int dim = nt2 * 16 + l15;
        const int vq = quad ^ ((dim >> 1) & 3);  // swizzled V chunk
        const bf16x8 vf = *(const bf16x8*)&Vs[cur][(dim * 4 + vq) * 8];
        O[nt2] = __builtin_amdgcn_mfma_f32_16x16x32_bf16(pf, vf, O[nt2], 0, 0, 0);
      }
    }
    __syncthreads();  // drains prefetch vmcnt + all waves done reading buf[cur]
    cur ^= 1;
  }
  for (int nt2 = 0; nt2 < 16; ++nt2)
    for (int r = 0; r < 4; ++r) {
      const float o = O[nt2][r] / lrow[r];
      Aout[(size_t)(q0 + wid * 16 + quad * 4 + r) * 2048 + h * 256 + nt2 * 16 + l15] = (__bf16)o;
    }
}

// ---------------------------------------------------------------------------
// O projection: out_f32[4096 x 2048] = attn_bf16 @ ow_f32^T (ow cast inline).
// grid (16, 32), block 256. [validated round 5]
// ---------------------------------------------------------------------------
__global__ __launch_bounds__(256, 2) void gemm_out(
    const __bf16* __restrict__ A, const float* __restrict__ B,
    float* __restrict__ C) {
  const int K = 2048, ldc = 2048;
  __shared__ __align__(16) __bf16 As[128 * 32];
  __shared__ __align__(16) __bf16 Bs[128 * 32];
  const int m0 = blockIdx.y * 128, n0 = blockIdx.x * 128;
  const int tid = threadIdx.x;
  const int wid = tid >> 6, lane = tid & 63, l15 = lane & 15, quad = lane >> 4;
  const int wm = wid >> 1, wn = wid & 1;

  f32x4v acc[4][4] = {};

  for (int kb = 0; kb < K; kb += 32) {
    for (int cc = 0; cc < 2; ++cc) {            // A: 512 bf16x8 chunks
      const int c = cc * 256 + tid;
      const int row = c >> 2, col = (c & 3) * 8;
      *(bf16x8*)&As[row * 32 + col] =
          *(const bf16x8*)(A + (size_t)(m0 + row) * K + kb + col);
    }
    for (int cc = 0; cc < 4; ++cc) {            // B: 1024 float4 chunks -> bf16
      const int c = cc * 256 + tid;
      const int row = c >> 3, col = (c & 7) * 4;
      const float4 bv = *(const float4*)(B + (size_t)(n0 + row) * K + kb + col);
      bf16x4 bh = {(__bf16)bv.x, (__bf16)bv.y, (__bf16)bv.z, (__bf16)bv.w};
      *(bf16x4*)&Bs[row * 32 + col] = bh;
    }
    __syncthreads();
    bf16x8 af[4], bfr[4];
    for (int mt = 0; mt < 4; ++mt)
      af[mt] = *(const bf16x8*)&As[(wm * 64 + mt * 16 + l15) * 32 + quad * 8];
    for (int nt = 0; nt < 4; ++nt)
      bfr[nt] = *(const bf16x8*)&Bs[(wn * 64 + nt * 16 + l15) * 32 + quad * 8];
    for (int mt = 0; mt < 4; ++mt)
      for (int nt = 0; nt < 4; ++nt)
        acc[mt][nt] = __builtin_amdgcn_mfma_f32_16x16x32_bf16(af[mt], bfr[nt], acc[mt][nt], 0, 0, 0);
    __syncthreads();
  }
  for (int mt = 0; mt < 4; ++mt)
    for (int nt = 0; nt < 4; ++nt) {
      const int row = m0 + wm * 64 + mt * 16 + quad * 4;
      const int col = n0 + wn * 64 + nt * 16 + l15;
      for (int r = 0; r < 4; ++r)
        C[(size_t)(row + r) * ldc + col] = acc[mt][nt][r];
    }
}

// ---------------------------------------------------------------------------
extern "C" void kernel_launch(void* const* d_in, const int* in_sizes, int n_in,
                              void* d_out, int out_size, void* d_ws, size_t ws_size,
                              hipStream_t stream) {
  const float* hidden = (const float*)d_in[0];
  const float* cosb   = (const float*)d_in[1];
  const float* sinb   = (const float*)d_in[2];
  const float* qw     = (const float*)d_in[3];
  const float* kw     = (const float*)d_in[4];
  const float* vw     = (const float*)d_in[5];
  const float* ow     = (const float*)d_in[6];
  const float* qnw    = (const float*)d_in[7];
  const float* knw    = (const float*)d_in[8];
  float* out = (float*)d_out;   // reference output dtype = float32

  // Workspace (128 MiB), lifetime-overlapped:
  //  [0,64)Mi   qkvf (f32) -> dead after norm_rope -> attn bf16 [0,16)
  //  [64,80)Mi  hh -> qh    [80,96)Mi  hl -> ql
  //  [96,112)Mi wh -> kh[96,104) kl[104,112)
  //  [112,128)Mi wl -> vT[112,120)
  const size_t MB = 1048576;
  char* ws = (char*)d_ws;
  float*  qkvf = (float*)ws;
  __bf16* attn = (__bf16*)ws;
  __bf16* hh   = (__bf16*)(ws + 64 * MB);
  __bf16* hl   = (__bf16*)(ws + 80 * MB);
  __bf16* wh   = (__bf16*)(ws + 96 * MB);
  __bf16* wl   = (__bf16*)(ws + 112 * MB);
  __bf16* qh   = (__bf16*)(ws + 64 * MB);
  __bf16* ql   = (__bf16*)(ws + 80 * MB);
  __bf16* kh   = (__bf16*)(ws + 96 * MB);
  __bf16* kl   = (__bf16*)(ws + 104 * MB);
  __bf16* vT   = (__bf16*)(ws + 112 * MB);

  // 0) f32 -> bf16 hi/lo split (hidden + packed [qw|kw|vw] weight planes)
  cvt_split<<<dim3(8192), 256, 0, stream>>>(hidden, hh, hl, 2097152);
  cvt_split<<<dim3(4096), 256, 0, stream>>>(qw, wh, wl, 1048576);
  cvt_split<<<dim3(2048), 256, 0, stream>>>(kw, wh + 4194304, wl + 4194304, 524288);
  cvt_split<<<dim3(2048), 256, 0, stream>>>(vw, wh + 6291456, wl + 6291456, 524288);

  // 1) QKV projection (split-precision MFMA, dbuf + corrected swizzle)
  gemm_qkv<<<dim3(1024), 256, 0, stream>>>(hh, hl, wh, wl, qkvf);
  // 2) f32 RMSNorm + RoPE; q/k hi-lo planes, v bf16 transposed
  norm_rope<<<dim3(4096, 16), 64, 0, stream>>>(qkvf, cosb, sinb, qnw, knw,
                                               qh, ql, kh, kl, vT);
  // 3) MFMA sliding-window flash attention (staged, dbuf, V/P swizzled)
  attn_mfma<<<dim3(32, 8), 512, 0, stream>>>(qh, ql, kh, kl, vT, attn);
  // 4) O projection -> f32 output
  gemm_out<<<dim3(16, 32), 256, 0, stream>>>(attn, ow, out);
}

// Round 5
// 562.830 us; speedup vs baseline: 1.0644x; 1.0644x over previous
//
#include <hip/hip_runtime.h>
#include <stdint.h>

typedef __bf16 bf16x8 __attribute__((ext_vector_type(8)));
typedef __bf16 bf16x4 __attribute__((ext_vector_type(4)));
typedef float f32x4v __attribute__((ext_vector_type(4)));

__device__ __forceinline__ void async_copy16(const void* gptr, void* ldsptr) {
  // wave-uniform LDS base; HW scatters lane i to base + i*16
  __builtin_amdgcn_global_load_lds(
      (const __attribute__((address_space(1))) void*)gptr,
      (__attribute__((address_space(3))) void*)ldsptr,
      16, 0, 0);
}

// ---------------------------------------------------------------------------
// f32 -> (hi, lo) bf16 split: hi = bf16(x), lo = bf16(x - hi). rep err ~2^-17.
// ---------------------------------------------------------------------------
__global__ __launch_bounds__(256) void cvt_split(
    const float* __restrict__ src, __bf16* __restrict__ hi,
    __bf16* __restrict__ lo, int n4) {
  const int i = blockIdx.x * 256 + threadIdx.x;
  if (i < n4) {
    const float4 v = ((const float4*)src)[i];
    float vv[4] = {v.x, v.y, v.z, v.w};
    bf16x4 h, l;
    for (int j = 0; j < 4; ++j) {
      h[j] = (__bf16)vv[j];
      l[j] = (__bf16)(vv[j] - (float)h[j]);
    }
    ((bf16x4*)hi)[i] = h;
    ((bf16x4*)lo)[i] = l;
  }
}

// ---------------------------------------------------------------------------
// QKV projection, round-5: round-3 structure (single-buffer 32KB, max TLP)
// + round-4's HW-validated conflict-free swizzle (slot ^= (row>>1)&3; gave
// SQ_LDS_BANK_CONFLICT==0 vs 1.678e7 for r1/r3 variants).
// Bank model (calibrated r1/r3/r4): conflict unit = 8 lanes/cycle in lane
// order; 64-B rows need the (row>>1) XOR so lanes 0..7 hit 8 distinct
// bank-quads. dbuf regressed (r4: -36us, TLP loss > prefetch gain) -> single
// buffer, 4 blocks/CU co-resident (grid == 4/CU exactly, VGPR 72 << 128 cap).
// n-stripe XCD map: XCD x owns n-panels [4x,4x+4) -> B stripe 4MB = one L2.
// grid 1024 (1D), block 256 (4 waves, 2x2, 4x4 16x16x32 MFMA, 64x64/wave).
// ---------------------------------------------------------------------------
__global__ __launch_bounds__(256, 4) void gemm_qkv(
    const __bf16* __restrict__ Ah, const __bf16* __restrict__ Al,
    const __bf16* __restrict__ Bh, const __bf16* __restrict__ Bl,
    float* __restrict__ C) {
  const int K = 2048, ldc = 4096;
  __shared__ __align__(16) __bf16 Ash[128 * 32];
  __shared__ __align__(16) __bf16 Asl[128 * 32];
  __shared__ __align__(16) __bf16 Bsh[128 * 32];
  __shared__ __align__(16) __bf16 Bsl[128 * 32];
  // n-stripe XCD map (round-robin dispatch: XCD = bid & 7):
  // XCD x -> n_blk = 4x + (c&3), m_blk = c>>2  (bijective over 1024 blocks)
  const int bid = blockIdx.x;
  const int xcd = bid & 7, c = bid >> 3;
  const int m0 = (c >> 2) * 128, n0 = (xcd * 4 + (c & 3)) * 128;
  const int tid = threadIdx.x;
  const int wid = tid >> 6, lane = tid & 63, l15 = lane & 15, quad = lane >> 4;
  const int wm = wid >> 1, wn = wid & 1;

  f32x4v acc[4][4] = {};

  for (int kb = 0; kb < K; kb += 32) {
    // 512 16B-chunks per plane; phys chunk cc (linear LDS) holds global
    // (row cc>>2, slot (cc&3)^((row>>1)&3))  [validated conflict-free]
    for (int it = 0; it < 2; ++it) {
      const int cc = (wid * 2 + it) * 64 + lane;
      const int row = cc >> 2;
      const int sc = (cc & 3) ^ ((row >> 1) & 3);
      const size_t ao = (size_t)(m0 + row) * K + kb + sc * 8;
      const size_t bo = (size_t)(n0 + row) * K + kb + sc * 8;
      const int dst = (wid * 2 + it) * 512;
      async_copy16(Ah + ao, &Ash[dst]);
      async_copy16(Al + ao, &Asl[dst]);
      async_copy16(Bh + bo, &Bsh[dst]);
      async_copy16(Bl + bo, &Bsl[dst]);
    }
    __syncthreads();  // drains vmcnt -> LDS tiles complete
    bf16x8 afh[4], afl[4], bfh[4], bfl[4];
    for (int mt = 0; mt < 4; ++mt) {
      const int r = wm * 64 + mt * 16 + l15;
      const int o = r * 32 + ((quad ^ ((r >> 1) & 3)) * 8);  // swizzled read
      afh[mt] = *(const bf16x8*)&Ash[o];
      afl[mt] = *(const bf16x8*)&Asl[o];
    }
    for (int nt = 0; nt < 4; ++nt) {
      const int r = wn * 64 + nt * 16 + l15;
      const int o = r * 32 + ((quad ^ ((r >> 1) & 3)) * 8);
      bfh[nt] = *(const bf16x8*)&Bsh[o];
      bfl[nt] = *(const bf16x8*)&Bsl[o];
    }
    for (int mt = 0; mt < 4; ++mt)
      for (int nt = 0; nt < 4; ++nt) {
        acc[mt][nt] = __builtin_amdgcn_mfma_f32_16x16x32_bf16(afh[mt], bfh[nt], acc[mt][nt], 0, 0, 0);
        acc[mt][nt] = __builtin_amdgcn_mfma_f32_16x16x32_bf16(afh[mt], bfl[nt], acc[mt][nt], 0, 0, 0);
        acc[mt][nt] = __builtin_amdgcn_mfma_f32_16x16x32_bf16(afl[mt], bfh[nt], acc[mt][nt], 0, 0, 0);
      }
    __syncthreads();
  }
  // C/D layout: col = lane&15, row = quad*4 + reg
  for (int mt = 0; mt < 4; ++mt)
    for (int nt = 0; nt < 4; ++nt) {
      const int row = m0 + wm * 64 + mt * 16 + quad * 4;
      const int col = n0 + wn * 64 + nt * 16 + l15;
      for (int r = 0; r < 4; ++r)
        C[(size_t)(row + r) * ldc + col] = acc[mt][nt][r];
    }
}

// ---------------------------------------------------------------------------
// RMSNorm + RoPE, f32 internal. grid (4096, 16), block 64 (one wave).
// chunk 0..7 -> q head (hi/lo planes), 8..11 -> k head (hi/lo planes),
// 12..15 -> v head (norm only, bf16, TRANSPOSED [kvh][256][S] for PV).
// [validated round 6]
// ---------------------------------------------------------------------------
__global__ __launch_bounds__(64) void norm_rope(
    const float* __restrict__ qkv, const float* __restrict__ cosb,
    const float* __restrict__ sinb, const float* __restrict__ qnw,
    const float* __restrict__ knw,
    __bf16* __restrict__ qh, __bf16* __restrict__ ql,
    __bf16* __restrict__ kh, __bf16* __restrict__ kl,
    __bf16* __restrict__ vT) {
  const int s = blockIdx.x, c = blockIdx.y, lane = threadIdx.x;
  const int d0 = lane * 4;
  const float4 xv = *(const float4*)(qkv + (size_t)s * 4096 + c * 256 + d0);
  float v[4] = {xv.x, xv.y, xv.z, xv.w};
  float ss = v[0] * v[0] + v[1] * v[1] + v[2] * v[2] + v[3] * v[3];
  for (int off = 1; off < 64; off <<= 1) ss += __shfl_xor(ss, off);
  const float rn = rsqrtf(ss * (1.0f / 256.0f) + 1e-6f);
  if (c < 12) {
    const float* w = (c < 8) ? qnw : knw;
    float y[4], yp[4];
    for (int j = 0; j < 4; ++j) y[j] = v[j] * rn * w[d0 + j];
    for (int j = 0; j < 4; ++j) yp[j] = __shfl_xor(y[j], 32);  // d partner +/-128
    for (int j = 0; j < 4; ++j) {
      const int d = d0 + j;
      const float rot = (d < 128) ? -yp[j] : yp[j];
      y[j] = y[j] * cosb[s * 256 + d] + rot * sinb[s * 256 + d];
    }
    const size_t o = (c < 8) ? ((size_t)c * 4096 + s) * 256 + d0
                             : ((size_t)(c - 8) * 4096 + s) * 256 + d0;
    __bf16* dh = (c < 8) ? qh : kh;
    __bf16* dl = (c < 8) ? ql : kl;
    bf16x4 hv, lv;
    for (int j = 0; j < 4; ++j) {
      hv[j] = (__bf16)y[j];
      lv[j] = (__bf16)(y[j] - (float)hv[j]);
    }
    *(bf16x4*)(dh + o) = hv;
    *(bf16x4*)(dl + o) = lv;
  } else {
    const int kvh = c - 12;
    for (int j = 0; j < 4; ++j)
      vT[(size_t)(kvh * 256 + d0 + j) * 4096 + s] = (__bf16)(v[j] * rn);
  }
}

// ---------------------------------------------------------------------------
// MFMA flash attention, sliding window 1024, causal, NO softmax scale.
// QK^T split-precision (hi*hi + hi*lo + lo*hi); PV bf16.
// 8-wave block, QBLK=128, KVBLK=32, double-buffered global_load_lds staging.
// V and P tiles use the stride-64B involution (chunk ^= (row>>1)&3); K keeps
// ^(row&7) (512-B rows, conflict-free). grid (32,8), block 512.
// [validated round 4]
// ---------------------------------------------------------------------------
__global__ __launch_bounds__(512, 2) void attn_mfma(
    const __bf16* __restrict__ Qh_, const __bf16* __restrict__ Ql_,
    const __bf16* __restrict__ Kh_, const __bf16* __restrict__ Kl_,
    const __bf16* __restrict__ VT, __bf16* __restrict__ Aout) {
  const int S = 4096, D = 256;
  // bijective remap: block (x + 32*y) -> XCD (bid&7) handles head (bid&7)
  const int bid = blockIdx.y * 32 + blockIdx.x;
  const int swz = (bid & 7) * 32 + (bid >> 3);
  const int h = swz >> 5;
  const int q0 = (swz & 31) * 128;
  const int tid = threadIdx.x;
  const int wid = tid >> 6, lane = tid & 63, l15 = lane & 15, quad = lane >> 4;
  const int kv = h >> 1;

  // double-buffered KV tiles: Kh/Kl [32 keys][256 d] (swizzled), V [256 d][32 keys]
  __shared__ __align__(16) __bf16 Ksh[2][32 * 256];
  __shared__ __align__(16) __bf16 Ksl[2][32 * 256];
  __shared__ __align__(16) __bf16 Vs[2][256 * 32];
  __shared__ __align__(16) __bf16 P[8][16][32];  // per-wave P C->A round-trip

  const __bf16* Khh = Kh_ + (size_t)kv * S * D;
  const __bf16* Khl = Kl_ + (size_t)kv * S * D;
  const __bf16* Vh = VT + (size_t)kv * D * S;

  // stage one 32-key tile: 1024 16B-chunks per plane, 2 chunks/thread/plane.
  // K chunk n: row=n>>5, c=n&31; LDS holds global chunk (row, c ^ (row&7)).
  // V chunk n: dim=n>>2, kc=n&3; LDS holds global chunk (dim, kc ^ ((dim>>1)&3)).
  auto stage = [&](int buf, int kt) {
    for (int set = 0; set < 2; ++set) {
      const int n = set * 512 + wid * 64 + lane;
      const int row = n >> 5, c = n & 31;
      const int sc = c ^ (row & 7);
      const size_t go = (size_t)(kt + row) * D + sc * 8;
      const int dst = (set * 512 + wid * 64) * 8;  // wave-uniform LDS base
      async_copy16(Khh + go, &Ksh[buf][dst]);
      async_copy16(Khl + go, &Ksl[buf][dst]);
      const int dim = n >> 2, kc = n & 3;
      const size_t vo = (size_t)dim * S + kt + (kc ^ ((dim >> 1) & 3)) * 8;
      async_copy16(Vh + vo, &Vs[buf][dst]);
    }
  };

  // Q fragments hi/lo (A-layout: m=lane&15, k=quad*8+j)
  bf16x8 qfh[8], qfl[8];
  {
    const size_t qoff =
        (size_t)h * S * D + (size_t)(q0 + wid * 16 + l15) * D + quad * 8;
    for (int ks = 0; ks < 8; ++ks) {
      qfh[ks] = *(const bf16x8*)(Qh_ + qoff + ks * 32);
      qfl[ks] = *(const bf16x8*)(Ql_ + qoff + ks * 32);
    }
  }

  f32x4v O[16] = {};
  float mrow[4] = {-1e30f, -1e30f, -1e30f, -1e30f};
  float lrow[4] = {0.f, 0.f, 0.f, 0.f};

  const int lo = (q0 >= 1024) ? (q0 - 1024) : 0;
  const int hi = q0 + 96;  // last 32-key tile base for QBLK=128
  const int iqmin = q0 + wid * 16;
  const int iqmax = iqmin + 15;

  stage(0, lo);
  __syncthreads();
  int cur = 0;

  for (int kt = lo; kt <= hi; kt += 32) {
    if (kt + 32 <= hi) stage(cur ^ 1, kt + 32);  // async prefetch next tile
    // wave-uniform skip of fully-masked tiles (must still hit the barrier)
    const bool active = (kt <= iqmax) && (kt + 31 >= iqmin - 1023);
    if (active) {
      // scores [16 q x 32 keys]: 2 n-tiles x 8 k-steps x 3 split terms
      f32x4v sa[2] = {};
      for (int nt = 0; nt < 2; ++nt) {
        const int row = nt * 16 + l15;
        const int rxk = row & 7;
        for (int ks = 0; ks < 8; ++ks) {
          const int c = (ks * 4 + quad) ^ rxk;
          const bf16x8 kh8 = *(const bf16x8*)&Ksh[cur][row * 256 + c * 8];
          const bf16x8 kl8 = *(const bf16x8*)&Ksl[cur][row * 256 + c * 8];
          sa[nt] = __builtin_amdgcn_mfma_f32_16x16x32_bf16(qfh[ks], kh8, sa[nt], 0, 0, 0);
          sa[nt] = __builtin_amdgcn_mfma_f32_16x16x32_bf16(qfh[ks], kl8, sa[nt], 0, 0, 0);
          sa[nt] = __builtin_amdgcn_mfma_f32_16x16x32_bf16(qfl[ks], kh8, sa[nt], 0, 0, 0);
        }
      }
      // online softmax (C-layout: row = quad*4+r, col = l15 within n-tile)
      float al[4];
      for (int r = 0; r < 4; ++r) {
        const int i = q0 + wid * 16 + quad * 4 + r;
        float mx = -1e30f;
        for (int nt = 0; nt < 2; ++nt) {
          const int j = kt + nt * 16 + l15;
          const float svv = ((j <= i) && (i - j < 1024)) ? sa[nt][r] : -1e30f;
          sa[nt][r] = svv;
          mx = fmaxf(mx, svv);
        }
        for (int off = 1; off < 16; off <<= 1) mx = fmaxf(mx, __shfl_xor(mx, off));
        const float mn = fmaxf(mrow[r], mx);
        al[r] = __expf(mrow[r] - mn);
        float ps = 0.f;
        const int prow = quad * 4 + r;
        const int px = (prow >> 1) & 3;
        for (int nt = 0; nt < 2; ++nt) {
          // explicit zero for fully-masked history (else exp(0)=1 garbage)
          const float p = (mn <= -1e29f) ? 0.f : __expf(sa[nt][r] - mn);
          const int pc = (nt * 2 + (l15 >> 3)) ^ px;  // swizzled P column chunk
          P[wid][prow][pc * 8 + (l15 & 7)] = (__bf16)p;
          ps += p;
        }
        for (int off = 1; off < 16; off <<= 1) ps += __shfl_xor(ps, off);
        lrow[r] = lrow[r] * al[r] + ps;
        mrow[r] = mn;
      }
      for (int nt2 = 0; nt2 < 16; ++nt2)
        for (int r = 0; r < 4; ++r) O[nt2][r] *= al[r];
      __asm__ volatile("s_waitcnt lgkmcnt(0)" ::: "memory");
      __builtin_amdgcn_sched_barrier(0);
      // PV: A = P[16x32] (A-layout from LDS, swizzled), B from staged V tile
      const int prx = (l15 >> 1) & 3;
      const bf16x8 pf = *(const bf16x8*)&P[wid][l15][(quad ^ prx) * 8];
      for (int nt2 = 0; nt2 < 16; ++nt2) {
        const int dim = nt2 * 16 + l15;
        const int vq = quad ^ ((dim >> 1) & 3);  // swizzled V chunk
        const bf16x8 vf = *(const bf16x8*)&Vs[cur][(dim * 4 + vq) * 8];
        O[nt2] = __builtin_amdgcn_mfma_f32_16x16x32_bf16(pf, vf, O[nt2], 0, 0, 0);
      }
    }
    __syncthreads();  // drains prefetch vmcnt + all waves done reading buf[cur]
    cur ^= 1;
  }
  for (int nt2 = 0; nt2 < 16; ++nt2)
    for (int r = 0; r < 4; ++r) {
      const float o = O[nt2][r] / lrow[r];
      Aout[(size_t)(q0 + wid * 16 + quad * 4 + r) * 2048 + h * 256 + nt2 * 16 + l15] = (__bf16)o;
    }
}

// ---------------------------------------------------------------------------
// O projection: out_f32[4096 x 2048] = attn_bf16 @ ow_f32^T (ow cast inline).
// Round-5: conflict-free swizzle on As/Bs (same validated (row>>1)&3
// involution -- reads were 8-way conflicted at stride-64B rows).
// grid (16, 32), block 256.
// ---------------------------------------------------------------------------
__global__ __launch_bounds__(256, 2) void gemm_out(
    const __bf16* __restrict__ A, const float* __restrict__ B,
    float* __restrict__ C) {
  const int K = 2048, ldc = 2048;
  __shared__ __align__(16) __bf16 As[128 * 32];
  __shared__ __align__(16) __bf16 Bs[128 * 32];
  const int m0 = blockIdx.y * 128, n0 = blockIdx.x * 128;
  const int tid = threadIdx.x;
  const int wid = tid >> 6, lane = tid & 63, l15 = lane & 15, quad = lane >> 4;
  const int wm = wid >> 1, wn = wid & 1;

  f32x4v acc[4][4] = {};

  for (int kb = 0; kb < K; kb += 32) {
    for (int cc = 0; cc < 2; ++cc) {            // A: 512 bf16x8 chunks
      const int c = cc * 256 + tid;
      const int row = c >> 2;
      const int col = ((c & 3) ^ ((row >> 1) & 3)) * 8;  // swizzled write
      *(bf16x8*)&As[row * 32 + col] =
          *(const bf16x8*)(A + (size_t)(m0 + row) * K + kb + (c & 3) * 8);
    }
    for (int cc = 0; cc < 4; ++cc) {            // B: 1024 float4 chunks -> bf16
      const int c = cc * 256 + tid;
      const int row = c >> 3;
      const int sl = ((c & 7) >> 1) ^ ((row >> 1) & 3);  // swizzled 16B slot
      const int col = sl * 8 + (c & 1) * 4;
      const float4 bv = *(const float4*)(B + (size_t)(n0 + row) * K + kb + (c & 7) * 4);
      bf16x4 bh = {(__bf16)bv.x, (__bf16)bv.y, (__bf16)bv.z, (__bf16)bv.w};
      *(bf16x4*)&Bs[row * 32 + col] = bh;
    }
    __syncthreads();
    bf16x8 af[4], bfr[4];
    for (int mt = 0; mt < 4; ++mt) {
      const int r = wm * 64 + mt * 16 + l15;
      af[mt] = *(const bf16x8*)&As[r * 32 + ((quad ^ ((r >> 1) & 3)) * 8)];
    }
    for (int nt = 0; nt < 4; ++nt) {
      const int r = wn * 64 + nt * 16 + l15;
      bfr[nt] = *(const bf16x8*)&Bs[r * 32 + ((quad ^ ((r >> 1) & 3)) * 8)];
    }
    for (int mt = 0; mt < 4; ++mt)
      for (int nt = 0; nt < 4; ++nt)
        acc[mt][nt] = __builtin_amdgcn_mfma_f32_16x16x32_bf16(af[mt], bfr[nt], acc[mt][nt], 0, 0, 0);
    __syncthreads();
  }
  for (int mt = 0; mt < 4; ++mt)
    for (int nt = 0; nt < 4; ++nt) {
      const int row = m0 + wm * 64 + mt * 16 + quad * 4;
      const int col = n0 + wn * 64 + nt * 16 + l15;
      for (int r = 0; r < 4; ++r)
        C[(size_t)(row + r) * ldc + col] = acc[mt][nt][r];
    }
}

// ---------------------------------------------------------------------------
extern "C" void kernel_launch(void* const* d_in, const int* in_sizes, int n_in,
                              void* d_out, int out_size, void* d_ws, size_t ws_size,
                              hipStream_t stream) {
  const float* hidden = (const float*)d_in[0];
  const float* cosb   = (const float*)d_in[1];
  const float* sinb   = (const float*)d_in[2];
  const float* qw     = (const float*)d_in[3];
  const float* kw     = (const float*)d_in[4];
  const float* vw     = (const float*)d_in[5];
  const float* ow     = (const float*)d_in[6];
  const float* qnw    = (const float*)d_in[7];
  const float* knw    = (const float*)d_in[8];
  float* out = (float*)d_out;   // reference output dtype = float32

  // Workspace (128 MiB), lifetime-overlapped:
  //  [0,64)Mi   qkvf (f32) -> dead after norm_rope -> attn bf16 [0,16)
  //  [64,80)Mi  hh -> qh    [80,96)Mi  hl -> ql
  //  [96,112)Mi wh -> kh[96,104) kl[104,112)
  //  [112,128)Mi wl -> vT[112,120)
  const size_t MB = 1048576;
  char* ws = (char*)d_ws;
  float*  qkvf = (float*)ws;
  __bf16* attn = (__bf16*)ws;
  __bf16* hh   = (__bf16*)(ws + 64 * MB);
  __bf16* hl   = (__bf16*)(ws + 80 * MB);
  __bf16* wh   = (__bf16*)(ws + 96 * MB);
  __bf16* wl   = (__bf16*)(ws + 112 * MB);
  __bf16* qh   = (__bf16*)(ws + 64 * MB);
  __bf16* ql   = (__bf16*)(ws + 80 * MB);
  __bf16* kh   = (__bf16*)(ws + 96 * MB);
  __bf16* kl   = (__bf16*)(ws + 104 * MB);
  __bf16* vT   = (__bf16*)(ws + 112 * MB);

  // 0) f32 -> bf16 hi/lo split (hidden + packed [qw|kw|vw] weight planes)
  cvt_split<<<dim3(8192), 256, 0, stream>>>(hidden, hh, hl, 2097152);
  cvt_split<<<dim3(4096), 256, 0, stream>>>(qw, wh, wl, 1048576);
  cvt_split<<<dim3(2048), 256, 0, stream>>>(kw, wh + 4194304, wl + 4194304, 524288);
  cvt_split<<<dim3(2048), 256, 0, stream>>>(vw, wh + 6291456, wl + 6291456, 524288);

  // 1) QKV projection (split-precision MFMA, single-buffer + validated swizzle)
  gemm_qkv<<<dim3(1024), 256, 0, stream>>>(hh, hl, wh, wl, qkvf);
  // 2) f32 RMSNorm + RoPE; q/k hi-lo planes, v bf16 transposed
  norm_rope<<<dim3(4096, 16), 64, 0, stream>>>(qkvf, cosb, sinb, qnw, knw,
                                               qh, ql, kh, kl, vT);
  // 3) MFMA sliding-window flash attention (staged, dbuf, V/P swizzled)
  attn_mfma<<<dim3(32, 8), 512, 0, stream>>>(qh, ql, kh, kl, vT, attn);
  // 4) O projection -> f32 output (swizzled LDS)
  gemm_out<<<dim3(16, 32), 256, 0, stream>>>(attn, ow, out);
}

// Round 6
// 519.514 us; speedup vs baseline: 1.1532x; 1.0834x over previous
//
#include <hip/hip_runtime.h>
#include <stdint.h>

typedef __bf16 bf16x8 __attribute__((ext_vector_type(8)));
typedef __bf16 bf16x4 __attribute__((ext_vector_type(4)));
typedef _Float16 f16x8 __attribute__((ext_vector_type(8)));
typedef _Float16 f16x4 __attribute__((ext_vector_type(4)));
typedef float f32x4v __attribute__((ext_vector_type(4)));

__device__ __forceinline__ void async_copy16(const void* gptr, void* ldsptr) {
  // wave-uniform LDS base; HW scatters lane i to base + i*16
  __builtin_amdgcn_global_load_lds(
      (const __attribute__((address_space(1))) void*)gptr,
      (__attribute__((address_space(3))) void*)ldsptr,
      16, 0, 0);
}

// ---------------------------------------------------------------------------
// f32 -> (hi, lo) bf16 split: hi = bf16(x), lo = bf16(x - hi). rep err ~2^-17.
// ---------------------------------------------------------------------------
__global__ __launch_bounds__(256) void cvt_split(
    const float* __restrict__ src, __bf16* __restrict__ hi,
    __bf16* __restrict__ lo, int n4) {
  const int i = blockIdx.x * 256 + threadIdx.x;
  if (i < n4) {
    const float4 v = ((const float4*)src)[i];
    float vv[4] = {v.x, v.y, v.z, v.w};
    bf16x4 h, l;
    for (int j = 0; j < 4; ++j) {
      h[j] = (__bf16)vv[j];
      l[j] = (__bf16)(vv[j] - (float)h[j]);
    }
    ((bf16x4*)hi)[i] = h;
    ((bf16x4*)lo)[i] = l;
  }
}

// ---------------------------------------------------------------------------
// f32 -> (hi, lo) f16 split: hi = f16(x), lo = f16(x - hi). ~22-bit mantissa.
// ---------------------------------------------------------------------------
__global__ __launch_bounds__(256) void cvt_split_f16(
    const float* __restrict__ src, _Float16* __restrict__ hi,
    _Float16* __restrict__ lo, int n4) {
  const int i = blockIdx.x * 256 + threadIdx.x;
  if (i < n4) {
    const float4 v = ((const float4*)src)[i];
    float vv[4] = {v.x, v.y, v.z, v.w};
    f16x4 h, l;
    for (int j = 0; j < 4; ++j) {
      h[j] = (_Float16)vv[j];
      l[j] = (_Float16)(vv[j] - (float)h[j]);
    }
    ((f16x4*)hi)[i] = h;
    ((f16x4*)lo)[i] = l;
  }
}

// ---------------------------------------------------------------------------
// f32 -> f16 single plane (weights: 12-bit mantissa, rel err ~2^-12).
// ---------------------------------------------------------------------------
__global__ __launch_bounds__(256) void cvt_f16(
    const float* __restrict__ src, _Float16* __restrict__ hi, int n4) {
  const int i = blockIdx.x * 256 + threadIdx.x;
  if (i < n4) {
    const float4 v = ((const float4*)src)[i];
    f16x4 h = {(_Float16)v.x, (_Float16)v.y, (_Float16)v.z, (_Float16)v.w};
    ((f16x4*)hi)[i] = h;
  }
}

// ---------------------------------------------------------------------------
// QKV projection, round-6: f16 2-term split. C = (Ah+Al) @ Bh^T where
// Ah/Al = f16 hi/lo of hidden (~22-bit), Bh = f16 weights (12-bit).
// Score-error analysis: k rel err 2^-12 -> qk abs err ~8e-3, below existing
// bf16 P/V quantization; gemm_out already tolerates bf16 (2^-9) o_w.
// vs round-5: 3 staged planes (24KB) not 4, 2 MFMA/pair not 3 ->
// LDS traffic -25%, MFMA -33%. Keeps r5's validated structure: single-buffer,
// 4 blocks/CU, conflict-free swizzle slot^=(row>>1)&3 (SQ_LDS_BANK_CONFLICT=0),
// n-stripe XCD map (XCD x owns n-panels [4x,4x+4), B stripe = one 4MB L2).
// grid 1024 (1D), block 256 (4 waves, 2x2, 4x4 16x16x32 MFMA, 64x64/wave).
// ---------------------------------------------------------------------------
__global__ __launch_bounds__(256, 4) void gemm_qkv(
    const _Float16* __restrict__ Ah, const _Float16* __restrict__ Al,
    const _Float16* __restrict__ Bh, float* __restrict__ C) {
  const int K = 2048, ldc = 4096;
  __shared__ __align__(16) _Float16 Ash[128 * 32];
  __shared__ __align__(16) _Float16 Asl[128 * 32];
  __shared__ __align__(16) _Float16 Bsh[128 * 32];
  // n-stripe XCD map (round-robin dispatch: XCD = bid & 7):
  // XCD x -> n_blk = 4x + (c&3), m_blk = c>>2  (bijective over 1024 blocks)
  const int bid = blockIdx.x;
  const int xcd = bid & 7, c = bid >> 3;
  const int m0 = (c >> 2) * 128, n0 = (xcd * 4 + (c & 3)) * 128;
  const int tid = threadIdx.x;
  const int wid = tid >> 6, lane = tid & 63, l15 = lane & 15, quad = lane >> 4;
  const int wm = wid >> 1, wn = wid & 1;

  f32x4v acc[4][4] = {};

  for (int kb = 0; kb < K; kb += 32) {
    // 512 16B-chunks per plane; phys chunk cc (linear LDS) holds global
    // (row cc>>2, slot (cc&3)^((row>>1)&3))  [validated conflict-free]
    for (int it = 0; it < 2; ++it) {
      const int cc = (wid * 2 + it) * 64 + lane;
      const int row = cc >> 2;
      const int sc = (cc & 3) ^ ((row >> 1) & 3);
      const size_t ao = (size_t)(m0 + row) * K + kb + sc * 8;
      const size_t bo = (size_t)(n0 + row) * K + kb + sc * 8;
      const int dst = (wid * 2 + it) * 512;
      async_copy16(Ah + ao, &Ash[dst]);
      async_copy16(Al + ao, &Asl[dst]);
      async_copy16(Bh + bo, &Bsh[dst]);
    }
    __syncthreads();  // drains vmcnt -> LDS tiles complete
    f16x8 afh[4], afl[4], bfh[4];
    for (int mt = 0; mt < 4; ++mt) {
      const int r = wm * 64 + mt * 16 + l15;
      const int o = r * 32 + ((quad ^ ((r >> 1) & 3)) * 8);  // swizzled read
      afh[mt] = *(const f16x8*)&Ash[o];
      afl[mt] = *(const f16x8*)&Asl[o];
    }
    for (int nt = 0; nt < 4; ++nt) {
      const int r = wn * 64 + nt * 16 + l15;
      const int o = r * 32 + ((quad ^ ((r >> 1) & 3)) * 8);
      bfh[nt] = *(const f16x8*)&Bsh[o];
    }
    for (int mt = 0; mt < 4; ++mt)
      for (int nt = 0; nt < 4; ++nt) {
        acc[mt][nt] = __builtin_amdgcn_mfma_f32_16x16x32_f16(afh[mt], bfh[nt], acc[mt][nt], 0, 0, 0);
        acc[mt][nt] = __builtin_amdgcn_mfma_f32_16x16x32_f16(afl[mt], bfh[nt], acc[mt][nt], 0, 0, 0);
      }
    __syncthreads();
  }
  // C/D layout: col = lane&15, row = quad*4 + reg
  for (int mt = 0; mt < 4; ++mt)
    for (int nt = 0; nt < 4; ++nt) {
      const int row = m0 + wm * 64 + mt * 16 + quad * 4;
      const int col = n0 + wn * 64 + nt * 16 + l15;
      for (int r = 0; r < 4; ++r)
        C[(size_t)(row + r) * ldc + col] = acc[mt][nt][r];
    }
}

// ---------------------------------------------------------------------------
// RMSNorm + RoPE, f32 internal. grid (4096, 16), block 64 (one wave).
// chunk 0..7 -> q head (hi/lo planes), 8..11 -> k head (hi/lo planes),
// 12..15 -> v head (norm only, bf16, TRANSPOSED [kvh][256][S] for PV).
// [validated round 6]
// ---------------------------------------------------------------------------
__global__ __launch_bounds__(64) void norm_rope(
    const float* __restrict__ qkv, const float* __restrict__ cosb,
    const float* __restrict__ sinb, const float* __restrict__ qnw,
    const float* __restrict__ knw,
    __bf16* __restrict__ qh, __bf16* __restrict__ ql,
    __bf16* __restrict__ kh, __bf16* __restrict__ kl,
    __bf16* __restrict__ vT) {
  const int s = blockIdx.x, c = blockIdx.y, lane = threadIdx.x;
  const int d0 = lane * 4;
  const float4 xv = *(const float4*)(qkv + (size_t)s * 4096 + c * 256 + d0);
  float v[4] = {xv.x, xv.y, xv.z, xv.w};
  float ss = v[0] * v[0] + v[1] * v[1] + v[2] * v[2] + v[3] * v[3];
  for (int off = 1; off < 64; off <<= 1) ss += __shfl_xor(ss, off);
  const float rn = rsqrtf(ss * (1.0f / 256.0f) + 1e-6f);
  if (c < 12) {
    const float* w = (c < 8) ? qnw : knw;
    float y[4], yp[4];
    for (int j = 0; j < 4; ++j) y[j] = v[j] * rn * w[d0 + j];
    for (int j = 0; j < 4; ++j) yp[j] = __shfl_xor(y[j], 32);  // d partner +/-128
    for (int j = 0; j < 4; ++j) {
      const int d = d0 + j;
      const float rot = (d < 128) ? -yp[j] : yp[j];
      y[j] = y[j] * cosb[s * 256 + d] + rot * sinb[s * 256 + d];
    }
    const size_t o = (c < 8) ? ((size_t)c * 4096 + s) * 256 + d0
                             : ((size_t)(c - 8) * 4096 + s) * 256 + d0;
    __bf16* dh = (c < 8) ? qh : kh;
    __bf16* dl = (c < 8) ? ql : kl;
    bf16x4 hv, lv;
    for (int j = 0; j < 4; ++j) {
      hv[j] = (__bf16)y[j];
      lv[j] = (__bf16)(y[j] - (float)hv[j]);
    }
    *(bf16x4*)(dh + o) = hv;
    *(bf16x4*)(dl + o) = lv;
  } else {
    const int kvh = c - 12;
    for (int j = 0; j < 4; ++j)
      vT[(size_t)(kvh * 256 + d0 + j) * 4096 + s] = (__bf16)(v[j] * rn);
  }
}

// ---------------------------------------------------------------------------
// MFMA flash attention, sliding window 1024, causal, NO softmax scale.
// QK^T split-precision (hi*hi + hi*lo + lo*hi); PV bf16.
// 8-wave block, QBLK=128, KVBLK=32, double-buffered global_load_lds staging.
// V and P tiles use the stride-64B involution (chunk ^= (row>>1)&3); K keeps
// ^(row&7) (512-B rows, conflict-free). grid (32,8), block 512.
// [validated round 4]
// ---------------------------------------------------------------------------
__global__ __launch_bounds__(512, 2) void attn_mfma(
    const __bf16* __restrict__ Qh_, const __bf16* __restrict__ Ql_,
    const __bf16* __restrict__ Kh_, const __bf16* __restrict__ Kl_,
    const __bf16* __restrict__ VT, __bf16* __restrict__ Aout) {
  const int S = 4096, D = 256;
  // bijective remap: block (x + 32*y) -> XCD (bid&7) handles head (bid&7)
  const int bid = blockIdx.y * 32 + blockIdx.x;
  const int swz = (bid & 7) * 32 + (bid >> 3);
  const int h = swz >> 5;
  const int q0 = (swz & 31) * 128;
  const int tid = threadIdx.x;
  const int wid = tid >> 6, lane = tid & 63, l15 = lane & 15, quad = lane >> 4;
  const int kv = h >> 1;

  // double-buffered KV tiles: Kh/Kl [32 keys][256 d] (swizzled), V [256 d][32 keys]
  __shared__ __align__(16) __bf16 Ksh[2][32 * 256];
  __shared__ __align__(16) __bf16 Ksl[2][32 * 256];
  __shared__ __align__(16) __bf16 Vs[2][256 * 32];
  __shared__ __align__(16) __bf16 P[8][16][32];  // per-wave P C->A round-trip

  const __bf16* Khh = Kh_ + (size_t)kv * S * D;
  const __bf16* Khl = Kl_ + (size_t)kv * S * D;
  const __bf16* Vh = VT + (size_t)kv * D * S;

  // stage one 32-key tile: 1024 16B-chunks per plane, 2 chunks/thread/plane.
  // K chunk n: row=n>>5, c=n&31; LDS holds global chunk (row, c ^ (row&7)).
  // V chunk n: dim=n>>2, kc=n&3; LDS holds global chunk (dim, kc ^ ((dim>>1)&3)).
  auto stage = [&](int buf, int kt) {
    for (int set = 0; set < 2; ++set) {
      const int n = set * 512 + wid * 64 + lane;
      const int row = n >> 5, c = n & 31;
      const int sc = c ^ (row & 7);
      const size_t go = (size_t)(kt + row) * D + sc * 8;
      const int dst = (set * 512 + wid * 64) * 8;  // wave-uniform LDS base
      async_copy16(Khh + go, &Ksh[buf][dst]);
      async_copy16(Khl + go, &Ksl[buf][dst]);
      const int dim = n >> 2, kc = n & 3;
      const size_t vo = (size_t)dim * S + kt + (kc ^ ((dim >> 1) & 3)) * 8;
      async_copy16(Vh + vo, &Vs[buf][dst]);
    }
  };

  // Q fragments hi/lo (A-layout: m=lane&15, k=quad*8+j)
  bf16x8 qfh[8], qfl[8];
  {
    const size_t qoff =
        (size_t)h * S * D + (size_t)(q0 + wid * 16 + l15) * D + quad * 8;
    for (int ks = 0; ks < 8; ++ks) {
      qfh[ks] = *(const bf16x8*)(Qh_ + qoff + ks * 32);
      qfl[ks] = *(const bf16x8*)(Ql_ + qoff + ks * 32);
    }
  }

  f32x4v O[16] = {};
  float mrow[4] = {-1e30f, -1e30f, -1e30f, -1e30f};
  float lrow[4] = {0.f, 0.f, 0.f, 0.f};

  const int lo = (q0 >= 1024) ? (q0 - 1024) : 0;
  const int hi = q0 + 96;  // last 32-key tile base for QBLK=128
  const int iqmin = q0 + wid * 16;
  const int iqmax = iqmin + 15;

  stage(0, lo);
  __syncthreads();
  int cur = 0;

  for (int kt = lo; kt <= hi; kt += 32) {
    if (kt + 32 <= hi) stage(cur ^ 1, kt + 32);  // async prefetch next tile
    // wave-uniform skip of fully-masked tiles (must still hit the barrier)
    const bool active = (kt <= iqmax) && (kt + 31 >= iqmin - 1023);
    if (active) {
      // scores [16 q x 32 keys]: 2 n-tiles x 8 k-steps x 3 split terms
      f32x4v sa[2] = {};
      for (int nt = 0; nt < 2; ++nt) {
        const int row = nt * 16 + l15;
        const int rxk = row & 7;
        for (int ks = 0; ks < 8; ++ks) {
          const int c = (ks * 4 + quad) ^ rxk;
          const bf16x8 kh8 = *(const bf16x8*)&Ksh[cur][row * 256 + c * 8];
          const bf16x8 kl8 = *(const bf16x8*)&Ksl[cur][row * 256 + c * 8];
          sa[nt] = __builtin_amdgcn_mfma_f32_16x16x32_bf16(qfh[ks], kh8, sa[nt], 0, 0, 0);
          sa[nt] = __builtin_amdgcn_mfma_f32_16x16x32_bf16(qfh[ks], kl8, sa[nt], 0, 0, 0);
          sa[nt] = __builtin_amdgcn_mfma_f32_16x16x32_bf16(qfl[ks], kh8, sa[nt], 0, 0, 0);
        }
      }
      // online softmax (C-layout: row = quad*4+r, col = l15 within n-tile)
      float al[4];
      for (int r = 0; r < 4; ++r) {
        const int i = q0 + wid * 16 + quad * 4 + r;
        float mx = -1e30f;
        for (int nt = 0; nt < 2; ++nt) {
          const int j = kt + nt * 16 + l15;
          const float svv = ((j <= i) && (i - j < 1024)) ? sa[nt][r] : -1e30f;
          sa[nt][r] = svv;
          mx = fmaxf(mx, svv);
        }
        for (int off = 1; off < 16; off <<= 1) mx = fmaxf(mx, __shfl_xor(mx, off));
        const float mn = fmaxf(mrow[r], mx);
        al[r] = __expf(mrow[r] - mn);
        float ps = 0.f;
        const int prow = quad * 4 + r;
        const int px = (prow >> 1) & 3;
        for (int nt = 0; nt < 2; ++nt) {
          // explicit zero for fully-masked history (else exp(0)=1 garbage)
          const float p = (mn <= -1e29f) ? 0.f : __expf(sa[nt][r] - mn);
          const int pc = (nt * 2 + (l15 >> 3)) ^ px;  // swizzled P column chunk
          P[wid][prow][pc * 8 + (l15 & 7)] = (__bf16)p;
          ps += p;
        }
        for (int off = 1; off < 16; off <<= 1) ps += __shfl_xor(ps, off);
        lrow[r] = lrow[r] * al[r] + ps;
        mrow[r] = mn;
      }
      for (int nt2 = 0; nt2 < 16; ++nt2)
        for (int r = 0; r < 4; ++r) O[nt2][r] *= al[r];
      __asm__ volatile("s_waitcnt lgkmcnt(0)" ::: "memory");
      __builtin_amdgcn_sched_barrier(0);
      // PV: A = P[16x32] (A-layout from LDS, swizzled), B from staged V tile
      const int prx = (l15 >> 1) & 3;
      const bf16x8 pf = *(const bf16x8*)&P[wid][l15][(quad ^ prx) * 8];
      for (int nt2 = 0; nt2 < 16; ++nt2) {
        const int dim = nt2 * 16 + l15;
        const int vq = quad ^ ((dim >> 1) & 3);  // swizzled V chunk
        const bf16x8 vf = *(const bf16x8*)&Vs[cur][(dim * 4 + vq) * 8];
        O[nt2] = __builtin_amdgcn_mfma_f32_16x16x32_bf16(pf, vf, O[nt2], 0, 0, 0);
      }
    }
    __syncthreads();  // drains prefetch vmcnt + all waves done reading buf[cur]
    cur ^= 1;
  }
  for (int nt2 = 0; nt2 < 16; ++nt2)
    for (int r = 0; r < 4; ++r) {
      const float o = O[nt2][r] / lrow[r];
      Aout[(size_t)(q0 + wid * 16 + quad * 4 + r) * 2048 + h * 256 + nt2 * 16 + l15] = (__bf16)o;
    }
}

// ---------------------------------------------------------------------------
// O projection: out_f32[4096 x 2048] = attn_bf16 @ ow_f32^T (ow cast inline).
// Conflict-free swizzle on As/Bs (validated (row>>1)&3 involution).
// grid (16, 32), block 256. [validated round 5]
// ---------------------------------------------------------------------------
__global__ __launch_bounds__(256, 2) void gemm_out(
    const __bf16* __restrict__ A, const float* __restrict__ B,
    float* __restrict__ C) {
  const int K = 2048, ldc = 2048;
  __shared__ __align__(16) __bf16 As[128 * 32];
  __shared__ __align__(16) __bf16 Bs[128 * 32];
  const int m0 = blockIdx.y * 128, n0 = blockIdx.x * 128;
  const int tid = threadIdx.x;
  const int wid = tid >> 6, lane = tid & 63, l15 = lane & 15, quad = lane >> 4;
  const int wm = wid >> 1, wn = wid & 1;

  f32x4v acc[4][4] = {};

  for (int kb = 0; kb < K; kb += 32) {
    for (int cc = 0; cc < 2; ++cc) {            // A: 512 bf16x8 chunks
      const int c = cc * 256 + tid;
      const int row = c >> 2;
      const int col = ((c & 3) ^ ((row >> 1) & 3)) * 8;  // swizzled write
      *(bf16x8*)&As[row * 32 + col] =
          *(const bf16x8*)(A + (size_t)(m0 + row) * K + kb + (c & 3) * 8);
    }
    for (int cc = 0; cc < 4; ++cc) {            // B: 1024 float4 chunks -> bf16
      const int c = cc * 256 + tid;
      const int row = c >> 3;
      const int sl = ((c & 7) >> 1) ^ ((row >> 1) & 3);  // swizzled 16B slot
      const int col = sl * 8 + (c & 1) * 4;
      const float4 bv = *(const float4*)(B + (size_t)(n0 + row) * K + kb + (c & 7) * 4);
      bf16x4 bh = {(__bf16)bv.x, (__bf16)bv.y, (__bf16)bv.z, (__bf16)bv.w};
      *(bf16x4*)&Bs[row * 32 + col] = bh;
    }
    __syncthreads();
    bf16x8 af[4], bfr[4];
    for (int mt = 0; mt < 4; ++mt) {
      const int r = wm * 64 + mt * 16 + l15;
      af[mt] = *(const bf16x8*)&As[r * 32 + ((quad ^ ((r >> 1) & 3)) * 8)];
    }
    for (int nt = 0; nt < 4; ++nt) {
      const int r = wn * 64 + nt * 16 + l15;
      bfr[nt] = *(const bf16x8*)&Bs[r * 32 + ((quad ^ ((r >> 1) & 3)) * 8)];
    }
    for (int mt = 0; mt < 4; ++mt)
      for (int nt = 0; nt < 4; ++nt)
        acc[mt][nt] = __builtin_amdgcn_mfma_f32_16x16x32_bf16(af[mt], bfr[nt], acc[mt][nt], 0, 0, 0);
    __syncthreads();
  }
  for (int mt = 0; mt < 4; ++mt)
    for (int nt = 0; nt < 4; ++nt) {
      const int row = m0 + wm * 64 + mt * 16 + quad * 4;
      const int col = n0 + wn * 64 + nt * 16 + l15;
      for (int r = 0; r < 4; ++r)
        C[(size_t)(row + r) * ldc + col] = acc[mt][nt][r];
    }
}

// ---------------------------------------------------------------------------
extern "C" void kernel_launch(void* const* d_in, const int* in_sizes, int n_in,
                              void* d_out, int out_size, void* d_ws, size_t ws_size,
                              hipStream_t stream) {
  const float* hidden = (const float*)d_in[0];
  const float* cosb   = (const float*)d_in[1];
  const float* sinb   = (const float*)d_in[2];
  const float* qw     = (const float*)d_in[3];
  const float* kw     = (const float*)d_in[4];
  const float* vw     = (const float*)d_in[5];
  const float* ow     = (const float*)d_in[6];
  const float* qnw    = (const float*)d_in[7];
  const float* knw    = (const float*)d_in[8];
  float* out = (float*)d_out;   // reference output dtype = float32

  // Workspace (128 MiB), lifetime-overlapped:
  //  [0,64)Mi   qkvf (f32) -> dead after norm_rope -> attn bf16 [0,16)
  //  [64,80)Mi  hh (f16) -> qh    [80,96)Mi  hl (f16) -> ql
  //  [96,112)Mi wh (f16, packed q|k|v) -> kh[96,104) kl[104,112)
  //  [112,120)Mi vT (written by norm_rope; region free before that)
  const size_t MB = 1048576;
  char* ws = (char*)d_ws;
  float*  qkvf = (float*)ws;
  __bf16* attn = (__bf16*)ws;
  _Float16* hh = (_Float16*)(ws + 64 * MB);
  _Float16* hl = (_Float16*)(ws + 80 * MB);
  _Float16* wh = (_Float16*)(ws + 96 * MB);
  __bf16* qh   = (__bf16*)(ws + 64 * MB);
  __bf16* ql   = (__bf16*)(ws + 80 * MB);
  __bf16* kh   = (__bf16*)(ws + 96 * MB);
  __bf16* kl   = (__bf16*)(ws + 104 * MB);
  __bf16* vT   = (__bf16*)(ws + 112 * MB);

  // 0) hidden -> f16 hi/lo planes; weights -> single f16 plane (packed q|k|v)
  cvt_split_f16<<<dim3(8192), 256, 0, stream>>>(hidden, hh, hl, 2097152);
  cvt_f16<<<dim3(4096), 256, 0, stream>>>(qw, wh, 1048576);
  cvt_f16<<<dim3(2048), 256, 0, stream>>>(kw, wh + 4194304, 524288);
  cvt_f16<<<dim3(2048), 256, 0, stream>>>(vw, wh + 6291456, 524288);

  // 1) QKV projection (f16 2-term split MFMA, single-buffer + validated swizzle)
  gemm_qkv<<<dim3(1024), 256, 0, stream>>>(hh, hl, wh, qkvf);
  // 2) f32 RMSNorm + RoPE; q/k hi-lo planes, v bf16 transposed
  norm_rope<<<dim3(4096, 16), 64, 0, stream>>>(qkvf, cosb, sinb, qnw, knw,
                                               qh, ql, kh, kl, vT);
  // 3) MFMA sliding-window flash attention (staged, dbuf, V/P swizzled)
  attn_mfma<<<dim3(32, 8), 512, 0, stream>>>(qh, ql, kh, kl, vT, attn);
  // 4) O projection -> f32 output (swizzled LDS)
  gemm_out<<<dim3(16, 32), 256, 0, stream>>>(attn, ow, out);
}

// Round 7
// 479.761 us; speedup vs baseline: 1.2487x; 1.0829x over previous
//
#include <hip/hip_runtime.h>
#include <stdint.h>

typedef __bf16 bf16x8 __attribute__((ext_vector_type(8)));
typedef __bf16 bf16x4 __attribute__((ext_vector_type(4)));
typedef _Float16 f16x8 __attribute__((ext_vector_type(8)));
typedef _Float16 f16x4 __attribute__((ext_vector_type(4)));
typedef float f32x4v __attribute__((ext_vector_type(4)));

__device__ __forceinline__ void async_copy16(const void* gptr, void* ldsptr) {
  // wave-uniform LDS base; HW scatters lane i to base + i*16
  __builtin_amdgcn_global_load_lds(
      (const __attribute__((address_space(1))) void*)gptr,
      (__attribute__((address_space(3))) void*)ldsptr,
      16, 0, 0);
}

// ---------------------------------------------------------------------------
// f32 -> (hi, lo) f16 split: hi = f16(x), lo = f16(x - hi). ~22-bit mantissa.
// ---------------------------------------------------------------------------
__global__ __launch_bounds__(256) void cvt_split_f16(
    const float* __restrict__ src, _Float16* __restrict__ hi,
    _Float16* __restrict__ lo, int n4) {
  const int i = blockIdx.x * 256 + threadIdx.x;
  if (i < n4) {
    const float4 v = ((const float4*)src)[i];
    float vv[4] = {v.x, v.y, v.z, v.w};
    f16x4 h, l;
    for (int j = 0; j < 4; ++j) {
      h[j] = (_Float16)vv[j];
      l[j] = (_Float16)(vv[j] - (float)h[j]);
    }
    ((f16x4*)hi)[i] = h;
    ((f16x4*)lo)[i] = l;
  }
}

// ---------------------------------------------------------------------------
// f32 -> f16 single plane (12-bit mantissa, rel err ~2^-12).
// ---------------------------------------------------------------------------
__global__ __launch_bounds__(256) void cvt_f16(
    const float* __restrict__ src, _Float16* __restrict__ hi, int n4) {
  const int i = blockIdx.x * 256 + threadIdx.x;
  if (i < n4) {
    const float4 v = ((const float4*)src)[i];
    f16x4 h = {(_Float16)v.x, (_Float16)v.y, (_Float16)v.z, (_Float16)v.w};
    ((f16x4*)hi)[i] = h;
  }
}

// ---------------------------------------------------------------------------
// QKV projection: f16 2-term split. C = (Ah+Al) @ Bh^T. [validated round 6:
// 148.5us, conflicts 0, absmax floor unchanged]
// Single-buffer 24KB LDS, 4 blocks/CU; swizzle slot^=(row>>1)&3 (64-B rows);
// n-stripe XCD map (XCD x owns n-panels [4x,4x+4), B stripe = one 4MB L2).
// grid 1024 (1D), block 256 (4 waves, 2x2, 4x4 16x16x32 MFMA, 64x64/wave).
// ---------------------------------------------------------------------------
__global__ __launch_bounds__(256, 4) void gemm_qkv(
    const _Float16* __restrict__ Ah, const _Float16* __restrict__ Al,
    const _Float16* __restrict__ Bh, float* __restrict__ C) {
  const int K = 2048, ldc = 4096;
  __shared__ __align__(16) _Float16 Ash[128 * 32];
  __shared__ __align__(16) _Float16 Asl[128 * 32];
  __shared__ __align__(16) _Float16 Bsh[128 * 32];
  const int bid = blockIdx.x;
  const int xcd = bid & 7, c = bid >> 3;
  const int m0 = (c >> 2) * 128, n0 = (xcd * 4 + (c & 3)) * 128;
  const int tid = threadIdx.x;
  const int wid = tid >> 6, lane = tid & 63, l15 = lane & 15, quad = lane >> 4;
  const int wm = wid >> 1, wn = wid & 1;

  f32x4v acc[4][4] = {};

  for (int kb = 0; kb < K; kb += 32) {
    for (int it = 0; it < 2; ++it) {
      const int cc = (wid * 2 + it) * 64 + lane;
      const int row = cc >> 2;
      const int sc = (cc & 3) ^ ((row >> 1) & 3);
      const size_t ao = (size_t)(m0 + row) * K + kb + sc * 8;
      const size_t bo = (size_t)(n0 + row) * K + kb + sc * 8;
      const int dst = (wid * 2 + it) * 512;
      async_copy16(Ah + ao, &Ash[dst]);
      async_copy16(Al + ao, &Asl[dst]);
      async_copy16(Bh + bo, &Bsh[dst]);
    }
    __syncthreads();  // drains vmcnt -> LDS tiles complete
    f16x8 afh[4], afl[4], bfh[4];
    for (int mt = 0; mt < 4; ++mt) {
      const int r = wm * 64 + mt * 16 + l15;
      const int o = r * 32 + ((quad ^ ((r >> 1) & 3)) * 8);  // swizzled read
      afh[mt] = *(const f16x8*)&Ash[o];
      afl[mt] = *(const f16x8*)&Asl[o];
    }
    for (int nt = 0; nt < 4; ++nt) {
      const int r = wn * 64 + nt * 16 + l15;
      const int o = r * 32 + ((quad ^ ((r >> 1) & 3)) * 8);
      bfh[nt] = *(const f16x8*)&Bsh[o];
    }
    for (int mt = 0; mt < 4; ++mt)
      for (int nt = 0; nt < 4; ++nt) {
        acc[mt][nt] = __builtin_amdgcn_mfma_f32_16x16x32_f16(afh[mt], bfh[nt], acc[mt][nt], 0, 0, 0);
        acc[mt][nt] = __builtin_amdgcn_mfma_f32_16x16x32_f16(afl[mt], bfh[nt], acc[mt][nt], 0, 0, 0);
      }
    __syncthreads();
  }
  // C/D layout: col = lane&15, row = quad*4 + reg
  for (int mt = 0; mt < 4; ++mt)
    for (int nt = 0; nt < 4; ++nt) {
      const int row = m0 + wm * 64 + mt * 16 + quad * 4;
      const int col = n0 + wn * 64 + nt * 16 + l15;
      for (int r = 0; r < 4; ++r)
        C[(size_t)(row + r) * ldc + col] = acc[mt][nt][r];
    }
}

// ---------------------------------------------------------------------------
// RMSNorm + RoPE, f32 internal. grid (4096, 16), block 64 (one wave).
// Round-7: all-f16 outputs. chunk 0..7 -> q head (f16 hi/lo planes),
// 8..11 -> k head (SINGLE f16 plane, 12-bit: the round-6-validated error
// magnitude), 12..15 -> v head (f16, TRANSPOSED [kvh][256][S] for PV).
// ---------------------------------------------------------------------------
__global__ __launch_bounds__(64) void norm_rope(
    const float* __restrict__ qkv, const float* __restrict__ cosb,
    const float* __restrict__ sinb, const float* __restrict__ qnw,
    const float* __restrict__ knw,
    _Float16* __restrict__ qh, _Float16* __restrict__ ql,
    _Float16* __restrict__ kh, _Float16* __restrict__ vT) {
  const int s = blockIdx.x, c = blockIdx.y, lane = threadIdx.x;
  const int d0 = lane * 4;
  const float4 xv = *(const float4*)(qkv + (size_t)s * 4096 + c * 256 + d0);
  float v[4] = {xv.x, xv.y, xv.z, xv.w};
  float ss = v[0] * v[0] + v[1] * v[1] + v[2] * v[2] + v[3] * v[3];
  for (int off = 1; off < 64; off <<= 1) ss += __shfl_xor(ss, off);
  const float rn = rsqrtf(ss * (1.0f / 256.0f) + 1e-6f);
  if (c < 12) {
    const float* w = (c < 8) ? qnw : knw;
    float y[4], yp[4];
    for (int j = 0; j < 4; ++j) y[j] = v[j] * rn * w[d0 + j];
    for (int j = 0; j < 4; ++j) yp[j] = __shfl_xor(y[j], 32);  // d partner +/-128
    for (int j = 0; j < 4; ++j) {
      const int d = d0 + j;
      const float rot = (d < 128) ? -yp[j] : yp[j];
      y[j] = y[j] * cosb[s * 256 + d] + rot * sinb[s * 256 + d];
    }
    if (c < 8) {
      const size_t o = ((size_t)c * 4096 + s) * 256 + d0;
      f16x4 hv, lv;
      for (int j = 0; j < 4; ++j) {
        hv[j] = (_Float16)y[j];
        lv[j] = (_Float16)(y[j] - (float)hv[j]);
      }
      *(f16x4*)(qh + o) = hv;
      *(f16x4*)(ql + o) = lv;
    } else {
      const size_t o = ((size_t)(c - 8) * 4096 + s) * 256 + d0;
      f16x4 hv;
      for (int j = 0; j < 4; ++j) hv[j] = (_Float16)y[j];
      *(f16x4*)(kh + o) = hv;
    }
  } else {
    const int kvh = c - 12;
    for (int j = 0; j < 4; ++j)
      vT[(size_t)(kvh * 256 + d0 + j) * 4096 + s] = (_Float16)(v[j] * rn);
  }
}

// ---------------------------------------------------------------------------
// MFMA flash attention, sliding window 1024, causal, NO softmax scale.
// Round-7: f16 throughout. QK^T 2-term (Qh+Ql f16 hi/lo x K single f16);
// PV f16 (P f16: more mantissa than bf16). Staged planes 3 -> 2; LDS
// 104 -> 72 KB (clears the 80KB 2-blocks/CU boundary). Swizzles validated:
// K ^(row&7) (512-B rows), V/P ^((row>>1)&3) (64-B rows), conflicts ~0.
// 8-wave block, QBLK=128, KVBLK=32, dbuf staging. grid (32,8), block 512.
// ---------------------------------------------------------------------------
__global__ __launch_bounds__(512, 2) void attn_mfma(
    const _Float16* __restrict__ Qh_, const _Float16* __restrict__ Ql_,
    const _Float16* __restrict__ Kh_, const _Float16* __restrict__ VT,
    _Float16* __restrict__ Aout) {
  const int S = 4096, D = 256;
  // bijective remap: block (x + 32*y) -> XCD (bid&7) handles head (bid&7)
  const int bid = blockIdx.y * 32 + blockIdx.x;
  const int swz = (bid & 7) * 32 + (bid >> 3);
  const int h = swz >> 5;
  const int q0 = (swz & 31) * 128;
  const int tid = threadIdx.x;
  const int wid = tid >> 6, lane = tid & 63, l15 = lane & 15, quad = lane >> 4;
  const int kv = h >> 1;

  // double-buffered KV tiles: K [32 keys][256 d] (swizzled), V [256 d][32 keys]
  __shared__ __align__(16) _Float16 Ksh[2][32 * 256];
  __shared__ __align__(16) _Float16 Vs[2][256 * 32];
  __shared__ __align__(16) _Float16 P[8][16][32];  // per-wave P C->A round-trip

  const _Float16* Khh = Kh_ + (size_t)kv * S * D;
  const _Float16* Vh = VT + (size_t)kv * D * S;

  // stage one 32-key tile: 1024 16B-chunks per plane, 2 chunks/thread/plane.
  // K chunk n: row=n>>5, c=n&31; LDS holds global chunk (row, c ^ (row&7)).
  // V chunk n: dim=n>>2, kc=n&3; LDS holds global chunk (dim, kc ^ ((dim>>1)&3)).
  auto stage = [&](int buf, int kt) {
    for (int set = 0; set < 2; ++set) {
      const int n = set * 512 + wid * 64 + lane;
      const int row = n >> 5, c = n & 31;
      const int sc = c ^ (row & 7);
      const size_t go = (size_t)(kt + row) * D + sc * 8;
      const int dst = (set * 512 + wid * 64) * 8;  // wave-uniform LDS base
      async_copy16(Khh + go, &Ksh[buf][dst]);
      const int dim = n >> 2, kc = n & 3;
      const size_t vo = (size_t)dim * S + kt + (kc ^ ((dim >> 1) & 3)) * 8;
      async_copy16(Vh + vo, &Vs[buf][dst]);
    }
  };

  // Q fragments hi/lo (A-layout: m=lane&15, k=quad*8+j)
  f16x8 qfh[8], qfl[8];
  {
    const size_t qoff =
        (size_t)h * S * D + (size_t)(q0 + wid * 16 + l15) * D + quad * 8;
    for (int ks = 0; ks < 8; ++ks) {
      qfh[ks] = *(const f16x8*)(Qh_ + qoff + ks * 32);
      qfl[ks] = *(const f16x8*)(Ql_ + qoff + ks * 32);
    }
  }

  f32x4v O[16] = {};
  float mrow[4] = {-1e30f, -1e30f, -1e30f, -1e30f};
  float lrow[4] = {0.f, 0.f, 0.f, 0.f};

  const int lo = (q0 >= 1024) ? (q0 - 1024) : 0;
  const int hi = q0 + 96;  // last 32-key tile base for QBLK=128
  const int iqmin = q0 + wid * 16;
  const int iqmax = iqmin + 15;

  stage(0, lo);
  __syncthreads();
  int cur = 0;

  for (int kt = lo; kt <= hi; kt += 32) {
    if (kt + 32 <= hi) stage(cur ^ 1, kt + 32);  // async prefetch next tile
    // wave-uniform skip of fully-masked tiles (must still hit the barrier)
    const bool active = (kt <= iqmax) && (kt + 31 >= iqmin - 1023);
    if (active) {
      // scores [16 q x 32 keys]: 2 n-tiles x 8 k-steps x 2 split terms
      f32x4v sa[2] = {};
      for (int nt = 0; nt < 2; ++nt) {
        const int row = nt * 16 + l15;
        const int rxk = row & 7;
        for (int ks = 0; ks < 8; ++ks) {
          const int c = (ks * 4 + quad) ^ rxk;
          const f16x8 kh8 = *(const f16x8*)&Ksh[cur][row * 256 + c * 8];
          sa[nt] = __builtin_amdgcn_mfma_f32_16x16x32_f16(qfh[ks], kh8, sa[nt], 0, 0, 0);
          sa[nt] = __builtin_amdgcn_mfma_f32_16x16x32_f16(qfl[ks], kh8, sa[nt], 0, 0, 0);
        }
      }
      // online softmax (C-layout: row = quad*4+r, col = l15 within n-tile)
      float al[4];
      for (int r = 0; r < 4; ++r) {
        const int i = q0 + wid * 16 + quad * 4 + r;
        float mx = -1e30f;
        for (int nt = 0; nt < 2; ++nt) {
          const int j = kt + nt * 16 + l15;
          const float svv = ((j <= i) && (i - j < 1024)) ? sa[nt][r] : -1e30f;
          sa[nt][r] = svv;
          mx = fmaxf(mx, svv);
        }
        for (int off = 1; off < 16; off <<= 1) mx = fmaxf(mx, __shfl_xor(mx, off));
        const float mn = fmaxf(mrow[r], mx);
        al[r] = __expf(mrow[r] - mn);
        float ps = 0.f;
        const int prow = quad * 4 + r;
        const int px = (prow >> 1) & 3;
        for (int nt = 0; nt < 2; ++nt) {
          // explicit zero for fully-masked history (else exp(0)=1 garbage)
          const float p = (mn <= -1e29f) ? 0.f : __expf(sa[nt][r] - mn);
          const int pc = (nt * 2 + (l15 >> 3)) ^ px;  // swizzled P column chunk
          P[wid][prow][pc * 8 + (l15 & 7)] = (_Float16)p;
          ps += p;
        }
        for (int off = 1; off < 16; off <<= 1) ps += __shfl_xor(ps, off);
        lrow[r] = lrow[r] * al[r] + ps;
        mrow[r] = mn;
      }
      for (int nt2 = 0; nt2 < 16; ++nt2)
        for (int r = 0; r < 4; ++r) O[nt2][r] *= al[r];
      __asm__ volatile("s_waitcnt lgkmcnt(0)" ::: "memory");
      __builtin_amdgcn_sched_barrier(0);
      // PV: A = P[16x32] (A-layout from LDS, swizzled), B from staged V tile
      const int prx = (l15 >> 1) & 3;
      const f16x8 pf = *(const f16x8*)&P[wid][l15][(quad ^ prx) * 8];
      for (int nt2 = 0; nt2 < 16; ++nt2) {
        const int dim = nt2 * 16 + l15;
        const int vq = quad ^ ((dim >> 1) & 3);  // swizzled V chunk
        const f16x8 vf = *(const f16x8*)&Vs[cur][(dim * 4 + vq) * 8];
        O[nt2] = __builtin_amdgcn_mfma_f32_16x16x32_f16(pf, vf, O[nt2], 0, 0, 0);
      }
    }
    __syncthreads();  // drains prefetch vmcnt + all waves done reading buf[cur]
    cur ^= 1;
  }
  for (int nt2 = 0; nt2 < 16; ++nt2)
    for (int r = 0; r < 4; ++r) {
      const float o = O[nt2][r] / lrow[r];
      Aout[(size_t)(q0 + wid * 16 + quad * 4 + r) * 2048 + h * 256 + nt2 * 16 + l15] = (_Float16)o;
    }
}

// ---------------------------------------------------------------------------
// O projection, round-7: rebuilt on the validated gemm_qkv structure.
// out_f32 = attn_f16 @ ow_f16^T, single-term f16 MFMA (ow 12-bit: strictly
// MORE accurate than the previous inline bf16 cast). global_load_lds staging
// both planes, conflict-free slot^=(row>>1)&3 swizzle, 16KB LDS, 4 blocks/CU.
// n-stripe XCD map over 512 blocks: XCD x owns n-blocks {2x, 2x+1} (1MB/L2).
// grid 512 (1D), block 256 (4 waves, 2x2, 4x4 16x16x32 MFMA, 64x64/wave).
// ---------------------------------------------------------------------------
__global__ __launch_bounds__(256, 4) void gemm_out(
    const _Float16* __restrict__ A, const _Float16* __restrict__ B,
    float* __restrict__ C) {
  const int K = 2048, ldc = 2048;
  __shared__ __align__(16) _Float16 As[128 * 32];
  __shared__ __align__(16) _Float16 Bs[128 * 32];
  const int bid = blockIdx.x;
  const int xcd = bid & 7, c = bid >> 3;
  const int m0 = (c >> 1) * 128, n0 = (xcd * 2 + (c & 1)) * 128;
  const int tid = threadIdx.x;
  const int wid = tid >> 6, lane = tid & 63, l15 = lane & 15, quad = lane >> 4;
  const int wm = wid >> 1, wn = wid & 1;

  f32x4v acc[4][4] = {};

  for (int kb = 0; kb < K; kb += 32) {
    for (int it = 0; it < 2; ++it) {
      const int cc = (wid * 2 + it) * 64 + lane;
      const int row = cc >> 2;
      const int sc = (cc & 3) ^ ((row >> 1) & 3);
      const size_t ao = (size_t)(m0 + row) * K + kb + sc * 8;
      const size_t bo = (size_t)(n0 + row) * K + kb + sc * 8;
      const int dst = (wid * 2 + it) * 512;
      async_copy16(A + ao, &As[dst]);
      async_copy16(B + bo, &Bs[dst]);
    }
    __syncthreads();
    f16x8 af[4], bfr[4];
    for (int mt = 0; mt < 4; ++mt) {
      const int r = wm * 64 + mt * 16 + l15;
      af[mt] = *(const f16x8*)&As[r * 32 + ((quad ^ ((r >> 1) & 3)) * 8)];
    }
    for (int nt = 0; nt < 4; ++nt) {
      const int r = wn * 64 + nt * 16 + l15;
      bfr[nt] = *(const f16x8*)&Bs[r * 32 + ((quad ^ ((r >> 1) & 3)) * 8)];
    }
    for (int mt = 0; mt < 4; ++mt)
      for (int nt = 0; nt < 4; ++nt)
        acc[mt][nt] = __builtin_amdgcn_mfma_f32_16x16x32_f16(af[mt], bfr[nt], acc[mt][nt], 0, 0, 0);
    __syncthreads();
  }
  for (int mt = 0; mt < 4; ++mt)
    for (int nt = 0; nt < 4; ++nt) {
      const int row = m0 + wm * 64 + mt * 16 + quad * 4;
      const int col = n0 + wn * 64 + nt * 16 + l15;
      for (int r = 0; r < 4; ++r)
        C[(size_t)(row + r) * ldc + col] = acc[mt][nt][r];
    }
}

// ---------------------------------------------------------------------------
extern "C" void kernel_launch(void* const* d_in, const int* in_sizes, int n_in,
                              void* d_out, int out_size, void* d_ws, size_t ws_size,
                              hipStream_t stream) {
  const float* hidden = (const float*)d_in[0];
  const float* cosb   = (const float*)d_in[1];
  const float* sinb   = (const float*)d_in[2];
  const float* qw     = (const float*)d_in[3];
  const float* kw     = (const float*)d_in[4];
  const float* vw     = (const float*)d_in[5];
  const float* ow     = (const float*)d_in[6];
  const float* qnw    = (const float*)d_in[7];
  const float* knw    = (const float*)d_in[8];
  float* out = (float*)d_out;   // reference output dtype = float32

  // Workspace (128 MiB), lifetime-overlapped (all f16 planes):
  //  [0,64)Mi   qkvf (f32) -> dead after norm_rope -> attn f16 [0,16)
  //  [64,80)Mi  hh -> qh    [80,96)Mi  hl -> ql
  //  [96,112)Mi wh (packed q|k|v weights) -> kh[96,104) vT[104,112)
  //  [112,120)Mi ow_f16 (written step 0, read step 4; region otherwise free)
  const size_t MB = 1048576;
  char* ws = (char*)d_ws;
  float*    qkvf = (float*)ws;
  _Float16* attn = (_Float16*)ws;
  _Float16* hh   = (_Float16*)(ws + 64 * MB);
  _Float16* hl   = (_Float16*)(ws + 80 * MB);
  _Float16* wh   = (_Float16*)(ws + 96 * MB);
  _Float16* qh   = (_Float16*)(ws + 64 * MB);
  _Float16* ql   = (_Float16*)(ws + 80 * MB);
  _Float16* kh   = (_Float16*)(ws + 96 * MB);
  _Float16* vT   = (_Float16*)(ws + 104 * MB);
  _Float16* owh  = (_Float16*)(ws + 112 * MB);

  // 0) hidden -> f16 hi/lo; weights (qkv packed + ow) -> single f16 planes
  cvt_split_f16<<<dim3(8192), 256, 0, stream>>>(hidden, hh, hl, 2097152);
  cvt_f16<<<dim3(4096), 256, 0, stream>>>(qw, wh, 1048576);
  cvt_f16<<<dim3(2048), 256, 0, stream>>>(kw, wh + 4194304, 524288);
  cvt_f16<<<dim3(2048), 256, 0, stream>>>(vw, wh + 6291456, 524288);
  cvt_f16<<<dim3(4096), 256, 0, stream>>>(ow, owh, 1048576);

  // 1) QKV projection (f16 2-term split MFMA, single-buffer + validated swizzle)
  gemm_qkv<<<dim3(1024), 256, 0, stream>>>(hh, hl, wh, qkvf);
  // 2) f32 RMSNorm + RoPE -> f16 q hi/lo, k single, vT
  norm_rope<<<dim3(4096, 16), 64, 0, stream>>>(qkvf, cosb, sinb, qnw, knw,
                                               qh, ql, kh, vT);
  // 3) MFMA sliding-window flash attention (all-f16, 2-term QK^T, 72KB LDS)
  attn_mfma<<<dim3(32, 8), 512, 0, stream>>>(qh, ql, kh, vT, attn);
  // 4) O projection -> f32 output (f16 single-term, async staging, 4 blk/CU)
  gemm_out<<<dim3(512), 256, 0, stream>>>(attn, owh, out);
}

// Round 8
// 473.865 us; speedup vs baseline: 1.2643x; 1.0124x over previous
//
#include <hip/hip_runtime.h>
#include <stdint.h>

typedef __bf16 bf16x8 __attribute__((ext_vector_type(8)));
typedef _Float16 f16x8 __attribute__((ext_vector_type(8)));
typedef _Float16 f16x4 __attribute__((ext_vector_type(4)));
typedef float f32x4v __attribute__((ext_vector_type(4)));

__device__ __forceinline__ void async_copy16(const void* gptr, void* ldsptr) {
  // wave-uniform LDS base; HW scatters lane i to base + i*16
  __builtin_amdgcn_global_load_lds(
      (const __attribute__((address_space(1))) void*)gptr,
      (__attribute__((address_space(3))) void*)ldsptr,
      16, 0, 0);
}

// ---------------------------------------------------------------------------
// f32 -> (hi, lo) f16 split: hi = f16(x), lo = f16(x - hi). ~22-bit mantissa.
// ---------------------------------------------------------------------------
__global__ __launch_bounds__(256) void cvt_split_f16(
    const float* __restrict__ src, _Float16* __restrict__ hi,
    _Float16* __restrict__ lo, int n4) {
  const int i = blockIdx.x * 256 + threadIdx.x;
  if (i < n4) {
    const float4 v = ((const float4*)src)[i];
    float vv[4] = {v.x, v.y, v.z, v.w};
    f16x4 h, l;
    for (int j = 0; j < 4; ++j) {
      h[j] = (_Float16)vv[j];
      l[j] = (_Float16)(vv[j] - (float)h[j]);
    }
    ((f16x4*)hi)[i] = h;
    ((f16x4*)lo)[i] = l;
  }
}

// ---------------------------------------------------------------------------
// Round-8: all 4 weight casts fused into one launch (q|k|v packed -> wh, ow
// -> owh). Region sizes are exact multiples of 256 float4s, no bounds checks.
// grid 12288, block 256.
// ---------------------------------------------------------------------------
__global__ __launch_bounds__(256) void cvt_weights(
    const float* __restrict__ qw, const float* __restrict__ kw,
    const float* __restrict__ vw, const float* __restrict__ ow,
    _Float16* __restrict__ wh, _Float16* __restrict__ owh) {
  const int b = blockIdx.x, tid = threadIdx.x;
  const float* src;
  _Float16* dst;
  int i;
  if (b < 4096)      { src = qw; dst = wh;           i = b * 256 + tid; }
  else if (b < 6144) { src = kw; dst = wh + 4194304; i = (b - 4096) * 256 + tid; }
  else if (b < 8192) { src = vw; dst = wh + 6291456; i = (b - 6144) * 256 + tid; }
  else               { src = ow; dst = owh;          i = (b - 8192) * 256 + tid; }
  const float4 v = ((const float4*)src)[i];
  f16x4 h = {(_Float16)v.x, (_Float16)v.y, (_Float16)v.z, (_Float16)v.w};
  ((f16x4*)dst)[i] = h;
}

// ---------------------------------------------------------------------------
// QKV projection: f16 2-term split. C = (Ah+Al) @ Bh^T. [validated rounds 6/7:
// 148us, conflicts 0, absmax floor unchanged]
// Single-buffer 24KB LDS, 4 blocks/CU; swizzle slot^=(row>>1)&3 (64-B rows);
// n-stripe XCD map (XCD x owns n-panels [4x,4x+4), B stripe = one 4MB L2).
// grid 1024 (1D), block 256 (4 waves, 2x2, 4x4 16x16x32 MFMA, 64x64/wave).
// ---------------------------------------------------------------------------
__global__ __launch_bounds__(256, 4) void gemm_qkv(
    const _Float16* __restrict__ Ah, const _Float16* __restrict__ Al,
    const _Float16* __restrict__ Bh, float* __restrict__ C) {
  const int K = 2048, ldc = 4096;
  __shared__ __align__(16) _Float16 Ash[128 * 32];
  __shared__ __align__(16) _Float16 Asl[128 * 32];
  __shared__ __align__(16) _Float16 Bsh[128 * 32];
  const int bid = blockIdx.x;
  const int xcd = bid & 7, c = bid >> 3;
  const int m0 = (c >> 2) * 128, n0 = (xcd * 4 + (c & 3)) * 128;
  const int tid = threadIdx.x;
  const int wid = tid >> 6, lane = tid & 63, l15 = lane & 15, quad = lane >> 4;
  const int wm = wid >> 1, wn = wid & 1;

  f32x4v acc[4][4] = {};

  for (int kb = 0; kb < K; kb += 32) {
    for (int it = 0; it < 2; ++it) {
      const int cc = (wid * 2 + it) * 64 + lane;
      const int row = cc >> 2;
      const int sc = (cc & 3) ^ ((row >> 1) & 3);
      const size_t ao = (size_t)(m0 + row) * K + kb + sc * 8;
      const size_t bo = (size_t)(n0 + row) * K + kb + sc * 8;
      const int dst = (wid * 2 + it) * 512;
      async_copy16(Ah + ao, &Ash[dst]);
      async_copy16(Al + ao, &Asl[dst]);
      async_copy16(Bh + bo, &Bsh[dst]);
    }
    __syncthreads();  // drains vmcnt -> LDS tiles complete
    f16x8 afh[4], afl[4], bfh[4];
    for (int mt = 0; mt < 4; ++mt) {
      const int r = wm * 64 + mt * 16 + l15;
      const int o = r * 32 + ((quad ^ ((r >> 1) & 3)) * 8);  // swizzled read
      afh[mt] = *(const f16x8*)&Ash[o];
      afl[mt] = *(const f16x8*)&Asl[o];
    }
    for (int nt = 0; nt < 4; ++nt) {
      const int r = wn * 64 + nt * 16 + l15;
      const int o = r * 32 + ((quad ^ ((r >> 1) & 3)) * 8);
      bfh[nt] = *(const f16x8*)&Bsh[o];
    }
    for (int mt = 0; mt < 4; ++mt)
      for (int nt = 0; nt < 4; ++nt) {
        acc[mt][nt] = __builtin_amdgcn_mfma_f32_16x16x32_f16(afh[mt], bfh[nt], acc[mt][nt], 0, 0, 0);
        acc[mt][nt] = __builtin_amdgcn_mfma_f32_16x16x32_f16(afl[mt], bfh[nt], acc[mt][nt], 0, 0, 0);
      }
    __syncthreads();
  }
  // C/D layout: col = lane&15, row = quad*4 + reg
  for (int mt = 0; mt < 4; ++mt)
    for (int nt = 0; nt < 4; ++nt) {
      const int row = m0 + wm * 64 + mt * 16 + quad * 4;
      const int col = n0 + wn * 64 + nt * 16 + l15;
      for (int r = 0; r < 4; ++r)
        C[(size_t)(row + r) * ldc + col] = acc[mt][nt][r];
    }
}

// ---------------------------------------------------------------------------
// RMSNorm + RoPE, f32 internal. Round-8: 256-thread blocks (4 waves, one
// chunk each; 4x fewer dispatches). grid (4096, 4).
// chunk 0..7 -> q head (f16 hi/lo), 8..11 -> k head (single f16),
// 12..15 -> v head (f16, TRANSPOSED [kvh][256][S] for PV).
// ---------------------------------------------------------------------------
__global__ __launch_bounds__(256) void norm_rope(
    const float* __restrict__ qkv, const float* __restrict__ cosb,
    const float* __restrict__ sinb, const float* __restrict__ qnw,
    const float* __restrict__ knw,
    _Float16* __restrict__ qh, _Float16* __restrict__ ql,
    _Float16* __restrict__ kh, _Float16* __restrict__ vT) {
  const int s = blockIdx.x;
  const int wid = threadIdx.x >> 6, lane = threadIdx.x & 63;
  const int c = blockIdx.y * 4 + wid;
  const int d0 = lane * 4;
  const float4 xv = *(const float4*)(qkv + (size_t)s * 4096 + c * 256 + d0);
  float v[4] = {xv.x, xv.y, xv.z, xv.w};
  float ss = v[0] * v[0] + v[1] * v[1] + v[2] * v[2] + v[3] * v[3];
  for (int off = 1; off < 64; off <<= 1) ss += __shfl_xor(ss, off);
  const float rn = rsqrtf(ss * (1.0f / 256.0f) + 1e-6f);
  if (c < 12) {
    const float* w = (c < 8) ? qnw : knw;
    float y[4], yp[4];
    for (int j = 0; j < 4; ++j) y[j] = v[j] * rn * w[d0 + j];
    for (int j = 0; j < 4; ++j) yp[j] = __shfl_xor(y[j], 32);  // d partner +/-128
    for (int j = 0; j < 4; ++j) {
      const int d = d0 + j;
      const float rot = (d < 128) ? -yp[j] : yp[j];
      y[j] = y[j] * cosb[s * 256 + d] + rot * sinb[s * 256 + d];
    }
    if (c < 8) {
      const size_t o = ((size_t)c * 4096 + s) * 256 + d0;
      f16x4 hv, lv;
      for (int j = 0; j < 4; ++j) {
        hv[j] = (_Float16)y[j];
        lv[j] = (_Float16)(y[j] - (float)hv[j]);
      }
      *(f16x4*)(qh + o) = hv;
      *(f16x4*)(ql + o) = lv;
    } else {
      const size_t o = ((size_t)(c - 8) * 4096 + s) * 256 + d0;
      f16x4 hv;
      for (int j = 0; j < 4; ++j) hv[j] = (_Float16)y[j];
      *(f16x4*)(kh + o) = hv;
    }
  } else {
    const int kvh = c - 12;
    for (int j = 0; j < 4; ++j)
      vT[(size_t)(kvh * 256 + d0 + j) * 4096 + s] = (_Float16)(v[j] * rn);
  }
}

// ---------------------------------------------------------------------------
// MFMA flash attention, sliding window 1024, causal, NO softmax scale.
// f16 throughout: QK^T 2-term (Qh+Ql x K single), PV f16. [validated round 7]
// Round-8: QBLK 128 -> 64, block 512 -> 256 (4 waves), grid 512 -> 2
// independent blocks/CU (was 1) -- barrier drains of one block hide under
// the other block's compute. LDS 68KB (K 32 + V 32 + P 4), 2x68 <= 160.
// Head-locked XCD map: h = x&7 -> XCD h caches its kv head's K+V (4MB = L2).
// Swizzles validated: K ^(row&7) (512-B rows), V/P ^((row>>1)&3) (64-B rows).
// ---------------------------------------------------------------------------
__global__ __launch_bounds__(256, 2) void attn_mfma(
    const _Float16* __restrict__ Qh_, const _Float16* __restrict__ Ql_,
    const _Float16* __restrict__ Kh_, const _Float16* __restrict__ VT,
    _Float16* __restrict__ Aout) {
  const int S = 4096, D = 256;
  // bijective head-locked remap: grid (64, 8); flat bid = y*64+x dispatches
  // round-robin -> XCD = x&7. Let h = x&7 (head pinned to XCD), q-block
  // index = y*8 + (x>>3) in [0,64).
  const int x = blockIdx.x, y = blockIdx.y;
  const int h = x & 7;
  const int q0 = (y * 8 + (x >> 3)) * 64;
  const int tid = threadIdx.x;
  const int wid = tid >> 6, lane = tid & 63, l15 = lane & 15, quad = lane >> 4;
  const int kv = h >> 1;

  // double-buffered KV tiles: K [32 keys][256 d] (swizzled), V [256 d][32 keys]
  __shared__ __align__(16) _Float16 Ksh[2][32 * 256];
  __shared__ __align__(16) _Float16 Vs[2][256 * 32];
  __shared__ __align__(16) _Float16 P[4][16][32];  // per-wave P C->A round-trip

  const _Float16* Khh = Kh_ + (size_t)kv * S * D;
  const _Float16* Vh = VT + (size_t)kv * D * S;

  // stage one 32-key tile: 1024 16B-chunks per plane, 4 chunks/thread/plane.
  // K chunk n: row=n>>5, c=n&31; LDS holds global chunk (row, c ^ (row&7)).
  // V chunk n: dim=n>>2, kc=n&3; LDS holds global chunk (dim, kc ^ ((dim>>1)&3)).
  auto stage = [&](int buf, int kt) {
    for (int set = 0; set < 4; ++set) {
      const int n = set * 256 + wid * 64 + lane;
      const int row = n >> 5, c = n & 31;
      const int sc = c ^ (row & 7);
      const size_t go = (size_t)(kt + row) * D + sc * 8;
      const int dst = (set * 256 + wid * 64) * 8;  // wave-uniform LDS base
      async_copy16(Khh + go, &Ksh[buf][dst]);
      const int dim = n >> 2, kc = n & 3;
      const size_t vo = (size_t)dim * S + kt + (kc ^ ((dim >> 1) & 3)) * 8;
      async_copy16(Vh + vo, &Vs[buf][dst]);
    }
  };

  // Q fragments hi/lo (A-layout: m=lane&15, k=quad*8+j)
  f16x8 qfh[8], qfl[8];
  {
    const size_t qoff =
        (size_t)h * S * D + (size_t)(q0 + wid * 16 + l15) * D + quad * 8;
    for (int ks = 0; ks < 8; ++ks) {
      qfh[ks] = *(const f16x8*)(Qh_ + qoff + ks * 32);
      qfl[ks] = *(const f16x8*)(Ql_ + qoff + ks * 32);
    }
  }

  f32x4v O[16] = {};
  float mrow[4] = {-1e30f, -1e30f, -1e30f, -1e30f};
  float lrow[4] = {0.f, 0.f, 0.f, 0.f};

  const int lo = (q0 >= 1024) ? (q0 - 1024) : 0;
  const int hi = q0 + 32;  // last 32-key tile base for QBLK=64
  const int iqmin = q0 + wid * 16;
  const int iqmax = iqmin + 15;

  stage(0, lo);
  __syncthreads();
  int cur = 0;

  for (int kt = lo; kt <= hi; kt += 32) {
    if (kt + 32 <= hi) stage(cur ^ 1, kt + 32);  // async prefetch next tile
    // wave-uniform skip of fully-masked tiles (must still hit the barrier)
    const bool active = (kt <= iqmax) && (kt + 31 >= iqmin - 1023);
    if (active) {
      // scores [16 q x 32 keys]: 2 n-tiles x 8 k-steps x 2 split terms
      f32x4v sa[2] = {};
      for (int nt = 0; nt < 2; ++nt) {
        const int row = nt * 16 + l15;
        const int rxk = row & 7;
        for (int ks = 0; ks < 8; ++ks) {
          const int c = (ks * 4 + quad) ^ rxk;
          const f16x8 kh8 = *(const f16x8*)&Ksh[cur][row * 256 + c * 8];
          sa[nt] = __builtin_amdgcn_mfma_f32_16x16x32_f16(qfh[ks], kh8, sa[nt], 0, 0, 0);
          sa[nt] = __builtin_amdgcn_mfma_f32_16x16x32_f16(qfl[ks], kh8, sa[nt], 0, 0, 0);
        }
      }
      // online softmax (C-layout: row = quad*4+r, col = l15 within n-tile)
      float al[4];
      for (int r = 0; r < 4; ++r) {
        const int i = q0 + wid * 16 + quad * 4 + r;
        float mx = -1e30f;
        for (int nt = 0; nt < 2; ++nt) {
          const int j = kt + nt * 16 + l15;
          const float svv = ((j <= i) && (i - j < 1024)) ? sa[nt][r] : -1e30f;
          sa[nt][r] = svv;
          mx = fmaxf(mx, svv);
        }
        for (int off = 1; off < 16; off <<= 1) mx = fmaxf(mx, __shfl_xor(mx, off));
        const float mn = fmaxf(mrow[r], mx);
        al[r] = __expf(mrow[r] - mn);
        float ps = 0.f;
        const int prow = quad * 4 + r;
        const int px = (prow >> 1) & 3;
        for (int nt = 0; nt < 2; ++nt) {
          // explicit zero for fully-masked history (else exp(0)=1 garbage)
          const float p = (mn <= -1e29f) ? 0.f : __expf(sa[nt][r] - mn);
          const int pc = (nt * 2 + (l15 >> 3)) ^ px;  // swizzled P column chunk
          P[wid][prow][pc * 8 + (l15 & 7)] = (_Float16)p;
          ps += p;
        }
        for (int off = 1; off < 16; off <<= 1) ps += __shfl_xor(ps, off);
        lrow[r] = lrow[r] * al[r] + ps;
        mrow[r] = mn;
      }
      for (int nt2 = 0; nt2 < 16; ++nt2)
        for (int r = 0; r < 4; ++r) O[nt2][r] *= al[r];
      __asm__ volatile("s_waitcnt lgkmcnt(0)" ::: "memory");
      __builtin_amdgcn_sched_barrier(0);
      // PV: A = P[16x32] (A-layout from LDS, swizzled), B from staged V tile
      const int prx = (l15 >> 1) & 3;
      const f16x8 pf = *(const f16x8*)&P[wid][l15][(quad ^ prx) * 8];
      for (int nt2 = 0; nt2 < 16; ++nt2) {
        const int dim = nt2 * 16 + l15;
        const int vq = quad ^ ((dim >> 1) & 3);  // swizzled V chunk
        const f16x8 vf = *(const f16x8*)&Vs[cur][(dim * 4 + vq) * 8];
        O[nt2] = __builtin_amdgcn_mfma_f32_16x16x32_f16(pf, vf, O[nt2], 0, 0, 0);
      }
    }
    __syncthreads();  // drains prefetch vmcnt + all waves done reading buf[cur]
    cur ^= 1;
  }
  for (int nt2 = 0; nt2 < 16; ++nt2)
    for (int r = 0; r < 4; ++r) {
      const float o = O[nt2][r] / lrow[r];
      Aout[(size_t)(q0 + wid * 16 + quad * 4 + r) * 2048 + h * 256 + nt2 * 16 + l15] = (_Float16)o;
    }
}

// ---------------------------------------------------------------------------
// O projection: out_f32 = attn_f16 @ ow_f16^T, single-term f16 MFMA.
// global_load_lds staging, conflict-free slot^=(row>>1)&3 swizzle, 16KB LDS,
// 4 blocks/CU. n-stripe XCD map over 512 blocks (1MB B-stripe per L2).
// grid 512 (1D), block 256. [validated round 7]
// ---------------------------------------------------------------------------
__global__ __launch_bounds__(256, 4) void gemm_out(
    const _Float16* __restrict__ A, const _Float16* __restrict__ B,
    float* __restrict__ C) {
  const int K = 2048, ldc = 2048;
  __shared__ __align__(16) _Float16 As[128 * 32];
  __shared__ __align__(16) _Float16 Bs[128 * 32];
  const int bid = blockIdx.x;
  const int xcd = bid & 7, c = bid >> 3;
  const int m0 = (c >> 1) * 128, n0 = (xcd * 2 + (c & 1)) * 128;
  const int tid = threadIdx.x;
  const int wid = tid >> 6, lane = tid & 63, l15 = lane & 15, quad = lane >> 4;
  const int wm = wid >> 1, wn = wid & 1;

  f32x4v acc[4][4] = {};

  for (int kb = 0; kb < K; kb += 32) {
    for (int it = 0; it < 2; ++it) {
      const int cc = (wid * 2 + it) * 64 + lane;
      const int row = cc >> 2;
      const int sc = (cc & 3) ^ ((row >> 1) & 3);
      const size_t ao = (size_t)(m0 + row) * K + kb + sc * 8;
      const size_t bo = (size_t)(n0 + row) * K + kb + sc * 8;
      const int dst = (wid * 2 + it) * 512;
      async_copy16(A + ao, &As[dst]);
      async_copy16(B + bo, &Bs[dst]);
    }
    __syncthreads();
    f16x8 af[4], bfr[4];
    for (int mt = 0; mt < 4; ++mt) {
      const int r = wm * 64 + mt * 16 + l15;
      af[mt] = *(const f16x8*)&As[r * 32 + ((quad ^ ((r >> 1) & 3)) * 8)];
    }
    for (int nt = 0; nt < 4; ++nt) {
      const int r = wn * 64 + nt * 16 + l15;
      bfr[nt] = *(const f16x8*)&Bs[r * 32 + ((quad ^ ((r >> 1) & 3)) * 8)];
    }
    for (int mt = 0; mt < 4; ++mt)
      for (int nt = 0; nt < 4; ++nt)
        acc[mt][nt] = __builtin_amdgcn_mfma_f32_16x16x32_f16(af[mt], bfr[nt], acc[mt][nt], 0, 0, 0);
    __syncthreads();
  }
  for (int mt = 0; mt < 4; ++mt)
    for (int nt = 0; nt < 4; ++nt) {
      const int row = m0 + wm * 64 + mt * 16 + quad * 4;
      const int col = n0 + wn * 64 + nt * 16 + l15;
      for (int r = 0; r < 4; ++r)
        C[(size_t)(row + r) * ldc + col] = acc[mt][nt][r];
    }
}

// ---------------------------------------------------------------------------
extern "C" void kernel_launch(void* const* d_in, const int* in_sizes, int n_in,
                              void* d_out, int out_size, void* d_ws, size_t ws_size,
                              hipStream_t stream) {
  const float* hidden = (const float*)d_in[0];
  const float* cosb   = (const float*)d_in[1];
  const float* sinb   = (const float*)d_in[2];
  const float* qw     = (const float*)d_in[3];
  const float* kw     = (const float*)d_in[4];
  const float* vw     = (const float*)d_in[5];
  const float* ow     = (const float*)d_in[6];
  const float* qnw    = (const float*)d_in[7];
  const float* knw    = (const float*)d_in[8];
  float* out = (float*)d_out;   // reference output dtype = float32

  // Workspace (128 MiB), lifetime-overlapped (all f16 planes):
  //  [0,64)Mi   qkvf (f32) -> dead after norm_rope -> attn f16 [0,16)
  //  [64,80)Mi  hh -> qh    [80,96)Mi  hl -> ql
  //  [96,112)Mi wh (packed q|k|v weights) -> kh[96,104) vT[104,112)
  //  [112,120)Mi ow_f16 (written step 0, read step 4)
  const size_t MB = 1048576;
  char* ws = (char*)d_ws;
  float*    qkvf = (float*)ws;
  _Float16* attn = (_Float16*)ws;
  _Float16* hh   = (_Float16*)(ws + 64 * MB);
  _Float16* hl   = (_Float16*)(ws + 80 * MB);
  _Float16* wh   = (_Float16*)(ws + 96 * MB);
  _Float16* qh   = (_Float16*)(ws + 64 * MB);
  _Float16* ql   = (_Float16*)(ws + 80 * MB);
  _Float16* kh   = (_Float16*)(ws + 96 * MB);
  _Float16* vT   = (_Float16*)(ws + 104 * MB);
  _Float16* owh  = (_Float16*)(ws + 112 * MB);

  // 0) hidden -> f16 hi/lo; all weights -> f16 in one fused launch
  cvt_split_f16<<<dim3(8192), 256, 0, stream>>>(hidden, hh, hl, 2097152);
  cvt_weights<<<dim3(12288), 256, 0, stream>>>(qw, kw, vw, ow, wh, owh);

  // 1) QKV projection (f16 2-term split MFMA, single-buffer + validated swizzle)
  gemm_qkv<<<dim3(1024), 256, 0, stream>>>(hh, hl, wh, qkvf);
  // 2) f32 RMSNorm + RoPE -> f16 q hi/lo, k single, vT (256-thread blocks)
  norm_rope<<<dim3(4096, 4), 256, 0, stream>>>(qkvf, cosb, sinb, qnw, knw,
                                               qh, ql, kh, vT);
  // 3) MFMA flash attention (QBLK=64, 2 blocks/CU, head-locked XCD map)
  attn_mfma<<<dim3(64, 8), 256, 0, stream>>>(qh, ql, kh, vT, attn);
  // 4) O projection -> f32 output (f16 single-term, async staging, 4 blk/CU)
  gemm_out<<<dim3(512), 256, 0, stream>>>(attn, owh, out);
}